// Round 4
// baseline (2401.564 us; speedup 1.0000x reference)
//
#include <hip/hip_runtime.h>
#include <cstdint>

// ---------------------------------------------------------------------------
// SnLocalDecoder: B=4, n=48, C=32. Round-4:
//  - Weight premix (k_wmix): v = mask*(t@(W0Wv) + tT@(W1Wv) + small@Wv) + bv.
//    Mask is a per-position scalar -> commutes with channel mixes. Kills the
//    s round-trip and 2 of 3 barriers in k_vw.
//  - Transpose-pair blocks (k_vw1/k_final): tile 4i x 4j x 8m staged together
//    with its transpose tile; row permutation serves both sweeps. t read ONCE.
//  - k_z: fused rows/cols/diag/tot reductions, NO atomics (per-(it,jt)
//    partial buffers summed in k_mix). k_red4 deleted.
// ---------------------------------------------------------------------------

namespace {

constexpr int nB = 4, nN = 48, nC = 32;
constexpr int SJ_ = nN * nC;            // 1536
constexpr int SI_ = nN * SJ_;           // 73728
constexpr long SB_ = (long)nN * SI_;    // 3538944
constexpr int RP_ = 294912;             // rows-partial stride (2 partials)
constexpr int CP_ = 294912;             // cols-partial stride (2 partials)
constexpr int TP_ = 6144;               // tot-partial stride  (4 partials)

__device__ __forceinline__ void decodePos(int p, int& b, int& i, int& j, int& m) {
    m = p % nN; int r = p / nN;
    j = r % nN; r /= nN;
    i = r % nN; b = r / nN;
}

// ---------------------------------------------------------------------------
__global__ __launch_bounds__(256) void k_prep(const float* __restrict__ x,
                                              const void* __restrict__ maskp,
                                              float* __restrict__ vm,
                                              float* __restrict__ S)
{
    __shared__ float vmL[nB * nN];
    const int tid = threadIdx.x;
    const unsigned int w0 = *(const unsigned int*)maskp;
    const bool is_byte = (w0 == 0x01010101u);   // bool-byte layout
    if (tid < nB * nN) {
        int b = tid / nN, i = tid % nN;
        long idx = ((long)(b * nN + i) * nN + i) * nN + i;   // mask[b,i,i,i]
        int bit;
        if (is_byte) bit = (((const unsigned char*)maskp)[idx] != 0);
        else         bit = (((const int*)maskp)[idx] != 0);
        float f = bit ? 1.f : 0.f;
        vm[tid] = f; vmL[tid] = f;
    }
    __syncthreads();
    if (tid < nB * nC) {
        int b = tid >> 5, c = tid & 31;
        float s = 0.f;
        for (int j = 0; j < nN; ++j) s += x[(b * nN + j) * nC + c] * vmL[b * nN + j];
        S[tid] = s;
    }
}

// ---------------------------------------------------------------------------
// Premixed weights: pm[l*2+s] = { (Wb_l[k] @ Ws)[32x32] k=0..5, bb_l @ Ws }.
// s=0: Ws=lvW (v), s=1: Ws=lwW (w). 6176 floats per set.
__global__ __launch_bounds__(256) void k_wmix(
    const float* __restrict__ bW0, const float* __restrict__ bb0,
    const float* __restrict__ lvW0, const float* __restrict__ lwW0,
    const float* __restrict__ bW1, const float* __restrict__ bb1,
    const float* __restrict__ lvW1, const float* __restrict__ lwW1,
    float* __restrict__ pm)
{
    const int blk = blockIdx.x;        // l*2+s
    const int l = blk >> 1, s = blk & 1;
    const float* Wb = l ? bW1 : bW0;
    const float* bb = l ? bb1 : bb0;
    const float* Ws = l ? (s ? lwW1 : lvW1) : (s ? lwW0 : lvW0);
    float* out = pm + blk * 6176;
    __shared__ float WsS[1024];
    for (int q = threadIdx.x; q < 1024; q += 256) WsS[q] = Ws[q];
    __syncthreads();
    for (int it = 0; it < 24; ++it) {
        int q = it * 256 + threadIdx.x;   // k*1024 + c*32 + d
        int d = q & 31, c = (q >> 5) & 31, k = q >> 10;
        float acc = 0.f;
        for (int e = 0; e < 32; ++e)
            acc = fmaf(Wb[k * 1024 + c * 32 + e], WsS[e * 32 + d], acc);
        out[q] = acc;
    }
    if (threadIdx.x < 32) {
        float acc = 0.f;
        for (int e = 0; e < 32; ++e) acc = fmaf(bb[e], WsS[e * 32 + threadIdx.x], acc);
        out[6144 + threadIdx.x] = acc;
    }
}

// ---------------------------------------------------------------------------
// Layer-0 small terms, closed form from x and S, with premixed W2..W5 + bias.
__global__ __launch_bounds__(256) void k_mix0(
    const float* __restrict__ x, const float* __restrict__ S,
    const float* __restrict__ Wb, const float* __restrict__ bias,
    float* __restrict__ drp, float* __restrict__ ccp, float* __restrict__ tbp)
{
    __shared__ float W2s[1024], W3s[1024], W4s[1024], W5s[1024], bs[32];
    const int tid = threadIdx.x;
    for (int q = tid; q < 1024; q += 256) {
        W2s[q] = Wb[2048 + q]; W3s[q] = Wb[3072 + q];
        W4s[q] = Wb[4096 + q]; W5s[q] = Wb[5120 + q];
    }
    if (tid < 32) bs[tid] = bias[tid];
    __syncthreads();
    const int id = blockIdx.x * 256 + tid;        // (b*48+i)*48+m
    const int m = id % nN; int r = id / nN; const int i = r % nN; const int b = r / nN;
    float odr[32], occ[32];
    #pragma unroll
    for (int d = 0; d < 32; ++d) { odr[d] = 0.f; occ[d] = 0.f; }
    for (int c2 = 0; c2 < 32; ++c2) {
        float xi = x[(b * nN + i) * nC + c2];
        float xm = x[(b * nN + m) * nC + c2];
        float sc = S[b * nC + c2];
        float A = xi * xi * xm;
        float R = xi * xm * sc * (1.f / nN);
        #pragma unroll
        for (int d = 0; d < 32; ++d) {
            odr[d] = fmaf(A, W2s[c2 * 32 + d], fmaf(R, W3s[c2 * 32 + d], odr[d]));
            occ[d] = fmaf(R, W4s[c2 * 32 + d], occ[d]);
        }
    }
    #pragma unroll
    for (int d = 0; d < 32; d += 4) {
        *(float4*)(drp + (size_t)id * 32 + d) = make_float4(odr[d], odr[d+1], odr[d+2], odr[d+3]);
        *(float4*)(ccp + (size_t)id * 32 + d) = make_float4(occ[d], occ[d+1], occ[d+2], occ[d+3]);
    }
    if (i == 0) {
        float ot[32];
        #pragma unroll
        for (int d = 0; d < 32; ++d) ot[d] = bs[d];
        for (int c2 = 0; c2 < 32; ++c2) {
            float xm = x[(b * nN + m) * nC + c2];
            float sc = S[b * nC + c2];
            float Tc = xm * sc * sc * (1.f / (nN * nN));
            #pragma unroll
            for (int d = 0; d < 32; ++d) ot[d] = fmaf(Tc, W5s[c2 * 32 + d], ot[d]);
        }
        for (int d = 0; d < 32; d += 4)
            *(float4*)(tbp + (size_t)(b * nN + m) * 32 + d) = make_float4(ot[d], ot[d+1], ot[d+2], ot[d+3]);
    }
}

// ---------------------------------------------------------------------------
// Small snconv2 terms from k_z's partial reductions (2 rows, 2 cols, 4 tot).
template <int DOUT>
__global__ __launch_bounds__(256) void k_mix(
    const float* __restrict__ dgp, const float* __restrict__ rw2,
    const float* __restrict__ cl2, const float* __restrict__ tt4,
    const float* __restrict__ Wb, const float* __restrict__ bias,
    float* __restrict__ drp, float* __restrict__ ccp, float* __restrict__ tbp)
{
    __shared__ float W2s[32 * DOUT], W3s[32 * DOUT], W4s[32 * DOUT], W5s[32 * DOUT], bs[DOUT];
    const int tid = threadIdx.x;
    for (int q = tid; q < 32 * DOUT; q += 256) {
        W2s[q] = Wb[2 * 32 * DOUT + q]; W3s[q] = Wb[3 * 32 * DOUT + q];
        W4s[q] = Wb[4 * 32 * DOUT + q]; W5s[q] = Wb[5 * 32 * DOUT + q];
    }
    if (tid < DOUT) bs[tid] = bias[tid];
    __syncthreads();
    const int id = blockIdx.x * 256 + tid;
    const int m = id % nN; int r = id / nN; const int i = r % nN; const int b = r / nN;
    float odr[DOUT], occ[DOUT];
    #pragma unroll
    for (int d = 0; d < DOUT; ++d) { odr[d] = 0.f; occ[d] = 0.f; }
    for (int c2 = 0; c2 < 32; ++c2) {
        size_t q = (size_t)id * 32 + c2;
        float dg = dgp[q];
        float rw = (rw2[q] + rw2[q + RP_]) * (1.f / nN);
        float cl = (cl2[q] + cl2[q + CP_]) * (1.f / nN);
        #pragma unroll
        for (int d = 0; d < DOUT; ++d) {
            odr[d] = fmaf(dg, W2s[c2 * DOUT + d], fmaf(rw, W3s[c2 * DOUT + d], odr[d]));
            occ[d] = fmaf(cl, W4s[c2 * DOUT + d], occ[d]);
        }
    }
    #pragma unroll
    for (int d = 0; d < DOUT; d += 4) {
        *(float4*)(drp + (size_t)id * DOUT + d) = make_float4(odr[d], odr[d+1], odr[d+2], odr[d+3]);
        *(float4*)(ccp + (size_t)id * DOUT + d) = make_float4(occ[d], occ[d+1], occ[d+2], occ[d+3]);
    }
    if (i == 0) {
        float ot[DOUT];
        #pragma unroll
        for (int d = 0; d < DOUT; ++d) ot[d] = bs[d];
        for (int c2 = 0; c2 < 32; ++c2) {
            size_t q = (size_t)(b * nN + m) * 32 + c2;
            float tv = (tt4[q] + tt4[q + TP_] + tt4[q + 2 * TP_] + tt4[q + 3 * TP_])
                       * (1.f / (nN * nN));
            #pragma unroll
            for (int d = 0; d < DOUT; ++d) ot[d] = fmaf(tv, W5s[c2 * DOUT + d], ot[d]);
        }
        for (int d = 0; d < DOUT; d += 4)
            *(float4*)(tbp + (size_t)(b * nN + m) * DOUT + d) = make_float4(ot[d], ot[d+1], ot[d+2], ot[d+3]);
    }
}

// ---------------------------------------------------------------------------
// Layer 0: t0 = xi*xj*xm (symmetric). v = mask*(t0@(W0+W1)Wv + small) + bv.
// Premixed: wc = P0+P1. 2 sweeps, 1 barrier.
__global__ __launch_bounds__(256, 4) void k_vw0(
    const float* __restrict__ x, const float* __restrict__ vm,
    const float* __restrict__ drv, const float* __restrict__ ccv, const float* __restrict__ tbv,
    const float* __restrict__ drw, const float* __restrict__ ccw, const float* __restrict__ tbw,
    const float* __restrict__ pmv, const float* __restrict__ pmw,   // premix bases (layer0)
    const float* __restrict__ bv, const float* __restrict__ bw,
    float* __restrict__ vout, float* __restrict__ wout)
{
    __shared__ float sA[128 * 36];
    const int tid = threadIdx.x;
    const long base = (long)blockIdx.x * 128;

    for (int rep = 0; rep < 4; ++rep) {
        int q = rep * 256 + tid; int pl = q >> 3, cq = q & 7;
        int p = (int)base + pl;
        int b, i, j, m; decodePos(p, b, i, j, m);
        float4 xi = *(const float4*)(x + (size_t)(b * nN + i) * nC + cq * 4);
        float4 xj = *(const float4*)(x + (size_t)(b * nN + j) * nC + cq * 4);
        float4 xm = *(const float4*)(x + (size_t)(b * nN + m) * nC + cq * 4);
        *(float4*)(sA + pl * 36 + cq * 4) =
            make_float4(xi.x * xj.x * xm.x, xi.y * xj.y * xm.y,
                        xi.z * xj.z * xm.z, xi.w * xj.w * xm.w);
    }
    __syncthreads();

    const int pt = tid >> 3, dq = tid & 7, d0 = dq * 4;
    float wc[32][4];
    float acc[4][4];

    auto zeroAcc = [&]() {
        #pragma unroll
        for (int a2 = 0; a2 < 4; ++a2)
            #pragma unroll
            for (int l = 0; l < 4; ++l) acc[a2][l] = 0.f;
    };
    auto loadWsum = [&](const float* Wp) {     // P0 + P1
        #pragma unroll
        for (int c2 = 0; c2 < 32; ++c2) {
            float4 a4 = *(const float4*)(Wp + c2 * nC + d0);
            float4 b4 = *(const float4*)(Wp + 1024 + c2 * nC + d0);
            wc[c2][0] = a4.x + b4.x; wc[c2][1] = a4.y + b4.y;
            wc[c2][2] = a4.z + b4.z; wc[c2][3] = a4.w + b4.w;
        }
    };
    auto sweep = [&]() {
        #pragma unroll
        for (int cq2 = 0; cq2 < 8; ++cq2) {
            #pragma unroll
            for (int l = 0; l < 4; ++l) {
                float4 tv = *(const float4*)(sA + (pt + 32 * l) * 36 + cq2 * 4);
                acc[l][0] = fmaf(tv.x, wc[cq2*4+0][0], acc[l][0]);
                acc[l][1] = fmaf(tv.x, wc[cq2*4+0][1], acc[l][1]);
                acc[l][2] = fmaf(tv.x, wc[cq2*4+0][2], acc[l][2]);
                acc[l][3] = fmaf(tv.x, wc[cq2*4+0][3], acc[l][3]);
                acc[l][0] = fmaf(tv.y, wc[cq2*4+1][0], acc[l][0]);
                acc[l][1] = fmaf(tv.y, wc[cq2*4+1][1], acc[l][1]);
                acc[l][2] = fmaf(tv.y, wc[cq2*4+1][2], acc[l][2]);
                acc[l][3] = fmaf(tv.y, wc[cq2*4+1][3], acc[l][3]);
                acc[l][0] = fmaf(tv.z, wc[cq2*4+2][0], acc[l][0]);
                acc[l][1] = fmaf(tv.z, wc[cq2*4+2][1], acc[l][1]);
                acc[l][2] = fmaf(tv.z, wc[cq2*4+2][2], acc[l][2]);
                acc[l][3] = fmaf(tv.z, wc[cq2*4+2][3], acc[l][3]);
                acc[l][0] = fmaf(tv.w, wc[cq2*4+3][0], acc[l][0]);
                acc[l][1] = fmaf(tv.w, wc[cq2*4+3][1], acc[l][1]);
                acc[l][2] = fmaf(tv.w, wc[cq2*4+3][2], acc[l][2]);
                acc[l][3] = fmaf(tv.w, wc[cq2*4+3][3], acc[l][3]);
            }
        }
    };
    auto finish = [&](const float* drS, const float* ccS, const float* tbS,
                      const float* bias, float* outp) {
        float4 b4 = *(const float4*)(bias + d0);
        #pragma unroll
        for (int l = 0; l < 4; ++l) {
            int p = (int)base + pt + 32 * l;
            int b, i, j, m; decodePos(p, b, i, j, m);
            float4 d4 = *(const float4*)(drS + (size_t)((b * nN + i) * nN + m) * nC + d0);
            float4 c4 = *(const float4*)(ccS + (size_t)((b * nN + j) * nN + m) * nC + d0);
            float4 t4 = *(const float4*)(tbS + (size_t)(b * nN + m) * nC + d0);
            float mk = vm[b * nN + i] * vm[b * nN + j] * vm[b * nN + m];
            float4 o4;
            o4.x = (acc[l][0] + d4.x + c4.x + t4.x) * mk + b4.x;
            o4.y = (acc[l][1] + d4.y + c4.y + t4.y) * mk + b4.y;
            o4.z = (acc[l][2] + d4.z + c4.z + t4.z) * mk + b4.z;
            o4.w = (acc[l][3] + d4.w + c4.w + t4.w) * mk + b4.w;
            *(float4*)(outp + (size_t)p * nC + d0) = o4;
        }
    };

    zeroAcc(); loadWsum(pmv); sweep(); finish(drv, ccv, tbv, bv, vout);
    zeroAcc(); loadWsum(pmw); sweep(); finish(drw, ccw, tbw, bw, wout);
}

// ---------------------------------------------------------------------------
// Layer 1: transpose-pair blocks. Tile = (i-grp 4, j-grp 4, m-chunk 8);
// block stages tileA and its transpose tileB, each read from HBM exactly once.
// Row permutation rT serves the W1 (transposed) sweeps.
__global__ __launch_bounds__(256, 4) void k_vw1(
    const float* __restrict__ t, const float* __restrict__ vm,
    const float* __restrict__ drv, const float* __restrict__ ccv, const float* __restrict__ tbv,
    const float* __restrict__ drw, const float* __restrict__ ccw, const float* __restrict__ tbw,
    const float* __restrict__ pmv, const float* __restrict__ pmw,   // premix bases (layer1)
    const float* __restrict__ bv, const float* __restrict__ bw,
    float* __restrict__ vout, float* __restrict__ wout)
{
    __shared__ float sA[128 * 36], sB[128 * 36];
    const int tid = threadIdx.x;
    const int pairIdx = blockIdx.x % 72;
    const int mc = (blockIdx.x / 72) % 6;
    const int b = blockIdx.x / 432;
    int gA, gB; bool selfp;
    if (pairIdx < 66) {
        int p = pairIdx, ga = 0;
        while (p >= 11 - ga) { p -= 11 - ga; ++ga; }
        gA = ga; gB = ga + 1 + p; selfp = false;
    } else {
        int e = pairIdx - 66; gA = 2 * e; gB = 2 * e + 1; selfp = true;
    }
    // tileA = (iA0, jA0); tileB = (iB0, jB0) = transpose grp (or 2nd diag tile)
    const int iA0 = gA * 4, jA0 = selfp ? gA * 4 : gB * 4;
    const int iB0 = gB * 4, jB0 = selfp ? gB * 4 : gA * 4;
    const int m0 = mc * 8;

    for (int rep = 0; rep < 4; ++rep) {
        int q = rep * 256 + tid; int pl = q >> 3, cq = q & 7;
        int di = pl >> 5, dj = (pl >> 3) & 3, dm = pl & 7;
        size_t pA = ((size_t)(b * nN + iA0 + di) * nN + (jA0 + dj)) * nN + m0 + dm;
        size_t pB = ((size_t)(b * nN + iB0 + di) * nN + (jB0 + dj)) * nN + m0 + dm;
        *(float4*)(sA + pl * 36 + cq * 4) = *(const float4*)(t + pA * nC + cq * 4);
        *(float4*)(sB + pl * 36 + cq * 4) = *(const float4*)(t + pB * nC + cq * 4);
    }
    __syncthreads();

    const int pt = tid >> 3, dq = tid & 7, d0 = dq * 4;
    int rows_[4], rowsT[4];
    #pragma unroll
    for (int l = 0; l < 4; ++l) {
        int r = pt + 32 * l;
        rows_[l] = r;
        rowsT[l] = ((r >> 3) & 3) * 32 + (r >> 5) * 8 + (r & 7);
    }
    float wc[32][4];
    float acc[4][4];

    auto zeroAcc = [&]() {
        #pragma unroll
        for (int a2 = 0; a2 < 4; ++a2)
            #pragma unroll
            for (int l = 0; l < 4; ++l) acc[a2][l] = 0.f;
    };
    auto loadW = [&](const float* Wp) {
        #pragma unroll
        for (int c2 = 0; c2 < 32; ++c2) {
            float4 q4 = *(const float4*)(Wp + c2 * nC + d0);
            wc[c2][0] = q4.x; wc[c2][1] = q4.y; wc[c2][2] = q4.z; wc[c2][3] = q4.w;
        }
    };
    auto sweepR = [&](const float* sp, const int* rws) {
        #pragma unroll
        for (int cq2 = 0; cq2 < 8; ++cq2) {
            #pragma unroll
            for (int l = 0; l < 4; ++l) {
                float4 tv = *(const float4*)(sp + rws[l] * 36 + cq2 * 4);
                acc[l][0] = fmaf(tv.x, wc[cq2*4+0][0], acc[l][0]);
                acc[l][1] = fmaf(tv.x, wc[cq2*4+0][1], acc[l][1]);
                acc[l][2] = fmaf(tv.x, wc[cq2*4+0][2], acc[l][2]);
                acc[l][3] = fmaf(tv.x, wc[cq2*4+0][3], acc[l][3]);
                acc[l][0] = fmaf(tv.y, wc[cq2*4+1][0], acc[l][0]);
                acc[l][1] = fmaf(tv.y, wc[cq2*4+1][1], acc[l][1]);
                acc[l][2] = fmaf(tv.y, wc[cq2*4+1][2], acc[l][2]);
                acc[l][3] = fmaf(tv.y, wc[cq2*4+1][3], acc[l][3]);
                acc[l][0] = fmaf(tv.z, wc[cq2*4+2][0], acc[l][0]);
                acc[l][1] = fmaf(tv.z, wc[cq2*4+2][1], acc[l][1]);
                acc[l][2] = fmaf(tv.z, wc[cq2*4+2][2], acc[l][2]);
                acc[l][3] = fmaf(tv.z, wc[cq2*4+2][3], acc[l][3]);
                acc[l][0] = fmaf(tv.w, wc[cq2*4+3][0], acc[l][0]);
                acc[l][1] = fmaf(tv.w, wc[cq2*4+3][1], acc[l][1]);
                acc[l][2] = fmaf(tv.w, wc[cq2*4+3][2], acc[l][2]);
                acc[l][3] = fmaf(tv.w, wc[cq2*4+3][3], acc[l][3]);
            }
        }
    };
    auto finish = [&](int i0, int j0,
                      const float* drS, const float* ccS, const float* tbS,
                      const float* bias, float* outp) {
        float4 b4 = *(const float4*)(bias + d0);
        #pragma unroll
        for (int l = 0; l < 4; ++l) {
            int r = rows_[l];
            int di = r >> 5, dj = (r >> 3) & 3, dm = r & 7;
            int gi = i0 + di, gj = j0 + dj, gm = m0 + dm;
            float4 d4 = *(const float4*)(drS + (size_t)((b * nN + gi) * nN + gm) * nC + d0);
            float4 c4 = *(const float4*)(ccS + (size_t)((b * nN + gj) * nN + gm) * nC + d0);
            float4 t4 = *(const float4*)(tbS + (size_t)(b * nN + gm) * nC + d0);
            float mk = vm[b * nN + gi] * vm[b * nN + gj] * vm[b * nN + gm];
            size_t pos = ((size_t)(b * nN + gi) * nN + gj) * nN + gm;
            float4 o4;
            o4.x = (acc[l][0] + d4.x + c4.x + t4.x) * mk + b4.x;
            o4.y = (acc[l][1] + d4.y + c4.y + t4.y) * mk + b4.y;
            o4.z = (acc[l][2] + d4.z + c4.z + t4.z) * mk + b4.z;
            o4.w = (acc[l][3] + d4.w + c4.w + t4.w) * mk + b4.w;
            *(float4*)(outp + pos * nC + d0) = o4;
        }
    };

    const float* sBT = selfp ? sA : sB;   // where tileA's transposed rows live
    const float* sAT = selfp ? sB : sA;   // where tileB's transposed rows live

    // tileA: v then w
    zeroAcc(); loadW(pmv); sweepR(sA, rows_); loadW(pmv + 1024); sweepR(sBT, rowsT);
    finish(iA0, jA0, drv, ccv, tbv, bv, vout);
    zeroAcc(); loadW(pmw); sweepR(sA, rows_); loadW(pmw + 1024); sweepR(sBT, rowsT);
    finish(iA0, jA0, drw, ccw, tbw, bw, wout);
    // tileB: v then w
    zeroAcc(); loadW(pmv); sweepR(sB, rows_); loadW(pmv + 1024); sweepR(sAT, rowsT);
    finish(iB0, jB0, drv, ccv, tbv, bv, vout);
    zeroAcc(); loadW(pmw); sweepR(sB, rows_); loadW(pmw + 1024); sweepR(sAT, rowsT);
    finish(iB0, jB0, drw, ccw, tbw, bw, wout);
}

// ---------------------------------------------------------------------------
// z = V*W/n per (b,m); o-mix + relu + mask -> t; fused rows/cols/diag/tot
// partial reductions (no atomics). Tile 24i x 24j x 32c; 768 blocks.
__global__ __launch_bounds__(256, 3) void k_z(
    const float* __restrict__ v, const float* __restrict__ w,
    const float* __restrict__ Wo, const float* __restrict__ bo,
    const float* __restrict__ vm, float* __restrict__ tout,
    float* __restrict__ rows2, float* __restrict__ cols2,
    float* __restrict__ diag_, float* __restrict__ tot4)
{
    __shared__ float lds[12912];           // 51648 B -> 3 blocks/CU
    float* Vt = lds;                       // [kk][c][i]: kk*807 + c*25 + i
    float* Wt = lds + 6456;
    constexpr int ZS = 34;                 // z/out row stride (per position)
    constexpr int ZWO = 9792;              // Wo area (288*34)
    constexpr int TOT0 = 10816;            // tot scratch [8][32]
    const int tid = threadIdx.x;
    const int blk = blockIdx.x;
    const int tl = blk & 3; const int bm = blk >> 2;
    const int it = tl >> 1, jt = tl & 1;
    const int b = bm / nN, m = bm % nN;
    const int c = tid & 31;
    const int g = tid >> 5;
    const int i3 = g >> 1, j2 = g & 1;     // i3 wave-uniform
    const int il0 = i3 * 6, jl0 = j2 * 12;
    const size_t posbase = (size_t)b * SB_ + (size_t)m * nC;

    float acc[6][12];
    #pragma unroll
    for (int l = 0; l < 6; ++l)
        #pragma unroll
        for (int u = 0; u < 12; ++u) acc[l][u] = 0.f;

    for (int kc = 0; kc < 6; ++kc) {
        if (kc) __syncthreads();
        #pragma unroll
        for (int rr = 0; rr < 6; ++rr) {          // V: 24i x 8k x 32c
            int q = rr * 256 + tid; int pos = q >> 3, cq = q & 7;
            int ii = pos >> 3, kk = pos & 7;
            float4 a = *(const float4*)(v + posbase + (size_t)(it * 24 + ii) * SI_
                                          + (size_t)(kc * 8 + kk) * SJ_ + cq * 4);
            float* dst = Vt + kk * 807 + (cq * 4) * 25 + ii;
            dst[0] = a.x; dst[25] = a.y; dst[50] = a.z; dst[75] = a.w;
        }
        #pragma unroll
        for (int rr = 0; rr < 6; ++rr) {          // W: 8k x 24j x 32c
            int q = rr * 256 + tid; int pos = q >> 3, cq = q & 7;
            int kk = pos / 24, jj = pos - kk * 24;
            float4 a = *(const float4*)(w + posbase + (size_t)(kc * 8 + kk) * SI_
                                          + (size_t)(jt * 24 + jj) * SJ_ + cq * 4);
            float* dst = Wt + kk * 807 + (cq * 4) * 25 + jj;
            dst[0] = a.x; dst[25] = a.y; dst[50] = a.z; dst[75] = a.w;
        }
        __syncthreads();
        #pragma unroll
        for (int kk = 0; kk < 8; ++kk) {
            float vf[6], wf[12];
            #pragma unroll
            for (int l = 0; l < 6; ++l) vf[l] = Vt[kk * 807 + c * 25 + il0 + l];
            #pragma unroll
            for (int u = 0; u < 12; ++u) wf[u] = Wt[kk * 807 + c * 25 + jl0 + u];
            #pragma unroll
            for (int l = 0; l < 6; ++l)
                #pragma unroll
                for (int u = 0; u < 12; ++u)
                    acc[l][u] = fmaf(vf[l], wf[u], acc[l][u]);
        }
    }
    __syncthreads();                               // staging area now reusable

    #pragma unroll
    for (int e = 0; e < 4; ++e)                    // Wo * (1/48)
        lds[ZWO + e * 256 + tid] = Wo[e * 256 + tid] * (1.f / nN);

    const int ptE = tid >> 3, dqE = tid & 7, d0 = dqE * 4;
    const float4 b4 = *(const float4*)(bo + d0);
    const float vmm = vm[b * nN + m];
    float colacc[3] = {0.f, 0.f, 0.f};
    float totacc = 0.f;

    for (int h = 0; h < 2; ++h) {
        if (h) __syncthreads();                    // protect h=0 reduction reads
        if ((i3 >> 1) == h) {                      // write this half's z
            int r0 = il0 - 12 * h;                 // 0 or 6
            #pragma unroll
            for (int l = 0; l < 6; ++l)
                #pragma unroll
                for (int u = 0; u < 12; ++u)
                    lds[((r0 + l) * 24 + jl0 + u) * ZS + c] = acc[l][u];
        }
        __syncthreads();                           // z + wo visible

        float oac[9][4];
        #pragma unroll
        for (int u = 0; u < 9; ++u)
            #pragma unroll
            for (int d = 0; d < 4; ++d) oac[u][d] = 0.f;
        #pragma unroll
        for (int c2 = 0; c2 < 32; ++c2) {
            float4 wo4 = *(const float4*)(lds + ZWO + c2 * 32 + d0);
            float zv[9];
            #pragma unroll
            for (int u = 0; u < 9; ++u) zv[u] = lds[(ptE * 9 + u) * ZS + c2];
            #pragma unroll
            for (int u = 0; u < 9; ++u) {
                oac[u][0] = fmaf(zv[u], wo4.x, oac[u][0]);
                oac[u][1] = fmaf(zv[u], wo4.y, oac[u][1]);
                oac[u][2] = fmaf(zv[u], wo4.z, oac[u][2]);
                oac[u][3] = fmaf(zv[u], wo4.w, oac[u][3]);
            }
        }
        __syncthreads();                           // all z reads done

        #pragma unroll
        for (int u = 0; u < 9; ++u) {
            int p = ptE * 9 + u;
            int rl = p / 24, jl = p - rl * 24;
            int gi = it * 24 + 12 * h + rl, gj = jt * 24 + jl;
            float mk = vm[b * nN + gi] * vm[b * nN + gj] * vmm;
            float4 o4;
            o4.x = fmaxf(oac[u][0] + b4.x, 0.f) * mk;
            o4.y = fmaxf(oac[u][1] + b4.y, 0.f) * mk;
            o4.z = fmaxf(oac[u][2] + b4.z, 0.f) * mk;
            o4.w = fmaxf(oac[u][3] + b4.w, 0.f) * mk;
            *(float4*)(tout + posbase + (size_t)gi * SI_ + (size_t)gj * SJ_ + d0) = o4;
            *(float2*)(lds + p * ZS + d0) = make_float2(o4.x, o4.y);
            *(float2*)(lds + p * ZS + d0 + 2) = make_float2(o4.z, o4.w);
        }
        __syncthreads();                           // out tile visible in LDS

        // rows (+diag, tot) over this half's 12 i's
        for (int rd = 0; rd < 2; ++rd) {
            int task = rd * 256 + tid;
            if (task < 384) {
                int i_r = task >> 5, c_r = task & 31;
                float rsum = 0.f;
                #pragma unroll
                for (int jl = 0; jl < 24; ++jl) rsum += lds[(i_r * 24 + jl) * ZS + c_r];
                int gi = it * 24 + 12 * h + i_r;
                rows2[(size_t)jt * RP_ + ((size_t)(b * nN + gi) * nN + m) * nC + c_r] = rsum;
                totacc += rsum;
                if (it == jt)
                    diag_[((size_t)(b * nN + gi) * nN + m) * nC + c_r] =
                        lds[(i_r * 24 + (12 * h + i_r)) * ZS + c_r];
            }
        }
        // cols partials accumulated across halves
        #pragma unroll
        for (int rr = 0; rr < 3; ++rr) {
            int task = rr * 256 + tid;
            int jl = task >> 5, c_c = task & 31;
            float csum = 0.f;
            #pragma unroll
            for (int il = 0; il < 12; ++il) csum += lds[(il * 24 + jl) * ZS + c_c];
            colacc[rr] += csum;
        }
    }

    #pragma unroll
    for (int rr = 0; rr < 3; ++rr) {
        int task = rr * 256 + tid;
        int jl = task >> 5, c_c = task & 31;
        cols2[(size_t)it * CP_ + ((size_t)(b * nN + jt * 24 + jl) * nN + m) * nC + c_c] = colacc[rr];
    }
    lds[TOT0 + g * 32 + c] = totacc;
    __syncthreads();
    if (tid < 32) {
        float s = 0.f;
        #pragma unroll
        for (int gg = 0; gg < 8; ++gg) s += lds[TOT0 + gg * 32 + tid];
        tot4[(size_t)(it * 2 + jt) * TP_ + (size_t)(b * nN + m) * nC + tid] = s;
    }
}

// ---------------------------------------------------------------------------
// Final snconv2 (C_out=16), transpose-pair blocks, direct to d_out.
__global__ __launch_bounds__(256, 4) void k_final(
    const float* __restrict__ t, const float* __restrict__ vm,
    const float* __restrict__ drp, const float* __restrict__ ccp, const float* __restrict__ tbp,
    const float* __restrict__ W0, const float* __restrict__ W1,
    float* __restrict__ out)
{
    __shared__ float sA[128 * 36], sB[128 * 36];
    const int tid = threadIdx.x;
    const int pairIdx = blockIdx.x % 72;
    const int mc = (blockIdx.x / 72) % 6;
    const int b = blockIdx.x / 432;
    int gA, gB; bool selfp;
    if (pairIdx < 66) {
        int p = pairIdx, ga = 0;
        while (p >= 11 - ga) { p -= 11 - ga; ++ga; }
        gA = ga; gB = ga + 1 + p; selfp = false;
    } else {
        int e = pairIdx - 66; gA = 2 * e; gB = 2 * e + 1; selfp = true;
    }
    const int iA0 = gA * 4, jA0 = selfp ? gA * 4 : gB * 4;
    const int iB0 = gB * 4, jB0 = selfp ? gB * 4 : gA * 4;
    const int m0 = mc * 8;

    for (int rep = 0; rep < 4; ++rep) {
        int q = rep * 256 + tid; int pl = q >> 3, cq = q & 7;
        int di = pl >> 5, dj = (pl >> 3) & 3, dm = pl & 7;
        size_t pA = ((size_t)(b * nN + iA0 + di) * nN + (jA0 + dj)) * nN + m0 + dm;
        size_t pB = ((size_t)(b * nN + iB0 + di) * nN + (jB0 + dj)) * nN + m0 + dm;
        *(float4*)(sA + pl * 36 + cq * 4) = *(const float4*)(t + pA * nC + cq * 4);
        *(float4*)(sB + pl * 36 + cq * 4) = *(const float4*)(t + pB * nC + cq * 4);
    }
    __syncthreads();

    const int pt = tid >> 3, dq = tid & 7, d0 = dq * 2;
    int rows_[4], rowsT[4];
    #pragma unroll
    for (int l = 0; l < 4; ++l) {
        int r = pt + 32 * l;
        rows_[l] = r;
        rowsT[l] = ((r >> 3) & 3) * 32 + (r >> 5) * 8 + (r & 7);
    }
    float wc[32][2], acc[4][2];

    auto zeroAcc = [&]() {
        #pragma unroll
        for (int l = 0; l < 4; ++l) { acc[l][0] = 0.f; acc[l][1] = 0.f; }
    };
    auto loadW = [&](const float* Wp) {
        #pragma unroll
        for (int c2 = 0; c2 < 32; ++c2) {
            float2 q2 = *(const float2*)(Wp + c2 * 16 + d0);
            wc[c2][0] = q2.x; wc[c2][1] = q2.y;
        }
    };
    auto sweepR = [&](const float* sp, const int* rws) {
        #pragma unroll
        for (int cq2 = 0; cq2 < 8; ++cq2) {
            #pragma unroll
            for (int l = 0; l < 4; ++l) {
                float4 tv = *(const float4*)(sp + rws[l] * 36 + cq2 * 4);
                acc[l][0] = fmaf(tv.x, wc[cq2*4+0][0], acc[l][0]);
                acc[l][1] = fmaf(tv.x, wc[cq2*4+0][1], acc[l][1]);
                acc[l][0] = fmaf(tv.y, wc[cq2*4+1][0], acc[l][0]);
                acc[l][1] = fmaf(tv.y, wc[cq2*4+1][1], acc[l][1]);
                acc[l][0] = fmaf(tv.z, wc[cq2*4+2][0], acc[l][0]);
                acc[l][1] = fmaf(tv.z, wc[cq2*4+2][1], acc[l][1]);
                acc[l][0] = fmaf(tv.w, wc[cq2*4+3][0], acc[l][0]);
                acc[l][1] = fmaf(tv.w, wc[cq2*4+3][1], acc[l][1]);
            }
        }
    };
    auto finish = [&](int i0, int j0) {
        #pragma unroll
        for (int l = 0; l < 4; ++l) {
            int r = rows_[l];
            int di = r >> 5, dj = (r >> 3) & 3, dm = r & 7;
            int gi = i0 + di, gj = j0 + dj, gm = m0 + dm;
            float2 d2 = *(const float2*)(drp + (size_t)((b * nN + gi) * nN + gm) * 16 + d0);
            float2 c2v = *(const float2*)(ccp + (size_t)((b * nN + gj) * nN + gm) * 16 + d0);
            float2 t2 = *(const float2*)(tbp + (size_t)(b * nN + gm) * 16 + d0);
            float mk = vm[b * nN + gi] * vm[b * nN + gj] * vm[b * nN + gm];
            size_t pos = ((size_t)(b * nN + gi) * nN + gj) * nN + gm;
            float2 o2;
            o2.x = (acc[l][0] + d2.x + c2v.x + t2.x) * mk;
            o2.y = (acc[l][1] + d2.y + c2v.y + t2.y) * mk;
            *(float2*)(out + pos * 16 + d0) = o2;
        }
    };

    const float* sBT = selfp ? sA : sB;
    const float* sAT = selfp ? sB : sA;

    zeroAcc(); loadW(W0); sweepR(sA, rows_); loadW(W1); sweepR(sBT, rowsT); finish(iA0, jA0);
    zeroAcc(); loadW(W0); sweepR(sB, rows_); loadW(W1); sweepR(sAT, rowsT); finish(iB0, jB0);
}

} // anonymous namespace

// ---------------------------------------------------------------------------
extern "C" void kernel_launch(void* const* d_in, const int* in_sizes, int n_in,
                              void* d_out, int out_size, void* d_ws, size_t ws_size,
                              hipStream_t stream)
{
    (void)in_sizes; (void)n_in; (void)out_size; (void)ws_size;
    const float* x    = (const float*)d_in[0];
    const void*  mask = d_in[1];
    const float* bW0  = (const float*)d_in[2];
    const float* bb0  = (const float*)d_in[3];
    const float* lvW0 = (const float*)d_in[4];
    const float* lvb0 = (const float*)d_in[5];
    const float* lwW0 = (const float*)d_in[6];
    const float* lwb0 = (const float*)d_in[7];
    const float* loW0 = (const float*)d_in[8];
    const float* lob0 = (const float*)d_in[9];
    const float* bW1  = (const float*)d_in[10];
    const float* bb1  = (const float*)d_in[11];
    const float* lvW1 = (const float*)d_in[12];
    const float* lvb1 = (const float*)d_in[13];
    const float* lwW1 = (const float*)d_in[14];
    const float* lwb1 = (const float*)d_in[15];
    const float* loW1 = (const float*)d_in[16];
    const float* lob1 = (const float*)d_in[17];
    const float* fW   = (const float*)d_in[18];
    const float* fb   = (const float*)d_in[19];

    float* ws  = (float*)d_ws;
    float* t     = ws;                          // 14155776
    float* v     = ws + 14155776L;
    float* w     = ws + 28311552L;
    float* rows2 = ws + 42467328L;              // 2 * 294912
    float* cols2 = rows2 + 2 * 294912;          // 2 * 294912
    float* diag  = cols2 + 2 * 294912;          // 294912
    float* tot4  = diag + 294912;               // 4 * 6144
    float* drv   = tot4 + 4 * 6144;             // 294912
    float* ccv   = drv + 294912;                // 294912
    float* tbv   = ccv + 294912;                // 6144
    float* drw   = tbv + 6144;                  // 294912
    float* ccw   = drw + 294912;                // 294912
    float* tbw   = ccw + 294912;                // 6144
    float* pm    = tbw + 6144;                  // 4 * 6176
    float* S     = pm + 4 * 6176;               // 128
    float* vm    = S + 128;                     // 192
    float* out   = (float*)d_out;

    const float* pmL0v = pm;                 // layer0 v-set
    const float* pmL0w = pm + 6176;          // layer0 w-set
    const float* pmL1v = pm + 2 * 6176;      // layer1 v-set
    const float* pmL1w = pm + 3 * 6176;      // layer1 w-set

    k_prep<<<1, 256, 0, stream>>>(x, mask, vm, S);
    k_wmix<<<4, 256, 0, stream>>>(bW0, bb0, lvW0, lwW0, bW1, bb1, lvW1, lwW1, pm);
    k_mix0<<<36, 256, 0, stream>>>(x, S, pmL0v, pmL0v + 6144, drv, ccv, tbv);
    k_mix0<<<36, 256, 0, stream>>>(x, S, pmL0w, pmL0w + 6144, drw, ccw, tbw);
    k_vw0<<<3456, 256, 0, stream>>>(x, vm, drv, ccv, tbv, drw, ccw, tbw,
                                    pmL0v, pmL0w, lvb0, lwb0, v, w);
    k_z<<<768, 256, 0, stream>>>(v, w, loW0, lob0, vm, t, rows2, cols2, diag, tot4);
    k_mix<32><<<36, 256, 0, stream>>>(diag, rows2, cols2, tot4, pmL1v, pmL1v + 6144, drv, ccv, tbv);
    k_mix<32><<<36, 256, 0, stream>>>(diag, rows2, cols2, tot4, pmL1w, pmL1w + 6144, drw, ccw, tbw);
    k_vw1<<<1728, 256, 0, stream>>>(t, vm, drv, ccv, tbv, drw, ccw, tbw,
                                    pmL1v, pmL1w, lvb1, lwb1, v, w);
    k_z<<<768, 256, 0, stream>>>(v, w, loW1, lob1, vm, t, rows2, cols2, diag, tot4);
    k_mix<16><<<36, 256, 0, stream>>>(diag, rows2, cols2, tot4, fW, fb, drv, ccv, tbv);
    k_final<<<1728, 256, 0, stream>>>(t, vm, drv, ccv, tbv, fW, fW + 512, out);
}

// Round 5
// 1594.588 us; speedup vs baseline: 1.5061x; 1.5061x over previous
//
#include <hip/hip_runtime.h>
#include <cstdint>

// ---------------------------------------------------------------------------
// SnLocalDecoder: B=4, n=48, C=32. Round-5:
//  - R4 post-mortem: per-thread wc[32][4] (128 fl) spilled to scratch under
//    the 64-VGPR allocation -> 4.5 GB HBM spill traffic in k_vw1. Fix: all
//    sweep weights staged in LDS (wave-shared, broadcast reads, ~60 VGPRs).
//  - Keep: weight premix (k_wmix), fused k_z reductions (no atomics,
//    per-(it,jt) partial buffers), k_red4 deleted.
//  - Revert transpose-pair blocks: R3-style staging (t + tT per block); the
//    tT re-read is L2-absorbed (R3 k_vw FETCH was only 76 MB).
// ---------------------------------------------------------------------------

namespace {

constexpr int nB = 4, nN = 48, nC = 32;
constexpr int SJ_ = nN * nC;            // 1536
constexpr int SI_ = nN * SJ_;           // 73728
constexpr long SB_ = (long)nN * SI_;    // 3538944
constexpr int RP_ = 294912;             // rows-partial stride (2 partials)
constexpr int CP_ = 294912;             // cols-partial stride (2 partials)
constexpr int TP_ = 6144;               // tot-partial stride  (4 partials)

__device__ __forceinline__ void decodePos(int p, int& b, int& i, int& j, int& m) {
    m = p % nN; int r = p / nN;
    j = r % nN; r /= nN;
    i = r % nN; b = r / nN;
}

// ---------------------------------------------------------------------------
__global__ __launch_bounds__(256) void k_prep(const float* __restrict__ x,
                                              const void* __restrict__ maskp,
                                              float* __restrict__ vm,
                                              float* __restrict__ S)
{
    __shared__ float vmL[nB * nN];
    const int tid = threadIdx.x;
    const unsigned int w0 = *(const unsigned int*)maskp;
    const bool is_byte = (w0 == 0x01010101u);   // bool-byte layout
    if (tid < nB * nN) {
        int b = tid / nN, i = tid % nN;
        long idx = ((long)(b * nN + i) * nN + i) * nN + i;   // mask[b,i,i,i]
        int bit;
        if (is_byte) bit = (((const unsigned char*)maskp)[idx] != 0);
        else         bit = (((const int*)maskp)[idx] != 0);
        float f = bit ? 1.f : 0.f;
        vm[tid] = f; vmL[tid] = f;
    }
    __syncthreads();
    if (tid < nB * nC) {
        int b = tid >> 5, c = tid & 31;
        float s = 0.f;
        for (int j = 0; j < nN; ++j) s += x[(b * nN + j) * nC + c] * vmL[b * nN + j];
        S[tid] = s;
    }
}

// ---------------------------------------------------------------------------
// Premixed weights: pm[l*2+s] = { (Wb_l[k] @ Ws)[32x32] k=0..5, bb_l @ Ws }.
__global__ __launch_bounds__(256) void k_wmix(
    const float* __restrict__ bW0, const float* __restrict__ bb0,
    const float* __restrict__ lvW0, const float* __restrict__ lwW0,
    const float* __restrict__ bW1, const float* __restrict__ bb1,
    const float* __restrict__ lvW1, const float* __restrict__ lwW1,
    float* __restrict__ pm)
{
    const int blk = blockIdx.x;        // l*2+s
    const int l = blk >> 1, s = blk & 1;
    const float* Wb = l ? bW1 : bW0;
    const float* bb = l ? bb1 : bb0;
    const float* Ws = l ? (s ? lwW1 : lvW1) : (s ? lwW0 : lvW0);
    float* out = pm + blk * 6176;
    __shared__ float WsS[1024];
    for (int q = threadIdx.x; q < 1024; q += 256) WsS[q] = Ws[q];
    __syncthreads();
    for (int it = 0; it < 24; ++it) {
        int q = it * 256 + threadIdx.x;   // k*1024 + c*32 + d
        int d = q & 31, c = (q >> 5) & 31, k = q >> 10;
        float acc = 0.f;
        for (int e = 0; e < 32; ++e)
            acc = fmaf(Wb[k * 1024 + c * 32 + e], WsS[e * 32 + d], acc);
        out[q] = acc;
    }
    if (threadIdx.x < 32) {
        float acc = 0.f;
        for (int e = 0; e < 32; ++e) acc = fmaf(bb[e], WsS[e * 32 + threadIdx.x], acc);
        out[6144 + threadIdx.x] = acc;
    }
}

// ---------------------------------------------------------------------------
// Layer-0 small terms, closed form from x and S, with premixed W2..W5 + bias.
__global__ __launch_bounds__(256) void k_mix0(
    const float* __restrict__ x, const float* __restrict__ S,
    const float* __restrict__ Wb, const float* __restrict__ bias,
    float* __restrict__ drp, float* __restrict__ ccp, float* __restrict__ tbp)
{
    __shared__ float W2s[1024], W3s[1024], W4s[1024], W5s[1024], bs[32];
    const int tid = threadIdx.x;
    for (int q = tid; q < 1024; q += 256) {
        W2s[q] = Wb[2048 + q]; W3s[q] = Wb[3072 + q];
        W4s[q] = Wb[4096 + q]; W5s[q] = Wb[5120 + q];
    }
    if (tid < 32) bs[tid] = bias[tid];
    __syncthreads();
    const int id = blockIdx.x * 256 + tid;        // (b*48+i)*48+m
    const int m = id % nN; int r = id / nN; const int i = r % nN; const int b = r / nN;
    float odr[32], occ[32];
    #pragma unroll
    for (int d = 0; d < 32; ++d) { odr[d] = 0.f; occ[d] = 0.f; }
    for (int c2 = 0; c2 < 32; ++c2) {
        float xi = x[(b * nN + i) * nC + c2];
        float xm = x[(b * nN + m) * nC + c2];
        float sc = S[b * nC + c2];
        float A = xi * xi * xm;
        float R = xi * xm * sc * (1.f / nN);
        #pragma unroll
        for (int d = 0; d < 32; ++d) {
            odr[d] = fmaf(A, W2s[c2 * 32 + d], fmaf(R, W3s[c2 * 32 + d], odr[d]));
            occ[d] = fmaf(R, W4s[c2 * 32 + d], occ[d]);
        }
    }
    #pragma unroll
    for (int d = 0; d < 32; d += 4) {
        *(float4*)(drp + (size_t)id * 32 + d) = make_float4(odr[d], odr[d+1], odr[d+2], odr[d+3]);
        *(float4*)(ccp + (size_t)id * 32 + d) = make_float4(occ[d], occ[d+1], occ[d+2], occ[d+3]);
    }
    if (i == 0) {
        float ot[32];
        #pragma unroll
        for (int d = 0; d < 32; ++d) ot[d] = bs[d];
        for (int c2 = 0; c2 < 32; ++c2) {
            float xm = x[(b * nN + m) * nC + c2];
            float sc = S[b * nC + c2];
            float Tc = xm * sc * sc * (1.f / (nN * nN));
            #pragma unroll
            for (int d = 0; d < 32; ++d) ot[d] = fmaf(Tc, W5s[c2 * 32 + d], ot[d]);
        }
        for (int d = 0; d < 32; d += 4)
            *(float4*)(tbp + (size_t)(b * nN + m) * 32 + d) = make_float4(ot[d], ot[d+1], ot[d+2], ot[d+3]);
    }
}

// ---------------------------------------------------------------------------
// Small snconv2 terms from k_z's partial reductions (2 rows, 2 cols, 4 tot).
template <int DOUT>
__global__ __launch_bounds__(256) void k_mix(
    const float* __restrict__ dgp, const float* __restrict__ rw2,
    const float* __restrict__ cl2, const float* __restrict__ tt4,
    const float* __restrict__ Wb, const float* __restrict__ bias,
    float* __restrict__ drp, float* __restrict__ ccp, float* __restrict__ tbp)
{
    __shared__ float W2s[32 * DOUT], W3s[32 * DOUT], W4s[32 * DOUT], W5s[32 * DOUT], bs[DOUT];
    const int tid = threadIdx.x;
    for (int q = tid; q < 32 * DOUT; q += 256) {
        W2s[q] = Wb[2 * 32 * DOUT + q]; W3s[q] = Wb[3 * 32 * DOUT + q];
        W4s[q] = Wb[4 * 32 * DOUT + q]; W5s[q] = Wb[5 * 32 * DOUT + q];
    }
    if (tid < DOUT) bs[tid] = bias[tid];
    __syncthreads();
    const int id = blockIdx.x * 256 + tid;
    const int m = id % nN; int r = id / nN; const int i = r % nN; const int b = r / nN;
    float odr[DOUT], occ[DOUT];
    #pragma unroll
    for (int d = 0; d < DOUT; ++d) { odr[d] = 0.f; occ[d] = 0.f; }
    for (int c2 = 0; c2 < 32; ++c2) {
        size_t q = (size_t)id * 32 + c2;
        float dg = dgp[q];
        float rw = (rw2[q] + rw2[q + RP_]) * (1.f / nN);
        float cl = (cl2[q] + cl2[q + CP_]) * (1.f / nN);
        #pragma unroll
        for (int d = 0; d < DOUT; ++d) {
            odr[d] = fmaf(dg, W2s[c2 * DOUT + d], fmaf(rw, W3s[c2 * DOUT + d], odr[d]));
            occ[d] = fmaf(cl, W4s[c2 * DOUT + d], occ[d]);
        }
    }
    #pragma unroll
    for (int d = 0; d < DOUT; d += 4) {
        *(float4*)(drp + (size_t)id * DOUT + d) = make_float4(odr[d], odr[d+1], odr[d+2], odr[d+3]);
        *(float4*)(ccp + (size_t)id * DOUT + d) = make_float4(occ[d], occ[d+1], occ[d+2], occ[d+3]);
    }
    if (i == 0) {
        float ot[DOUT];
        #pragma unroll
        for (int d = 0; d < DOUT; ++d) ot[d] = bs[d];
        for (int c2 = 0; c2 < 32; ++c2) {
            size_t q = (size_t)(b * nN + m) * 32 + c2;
            float tv = (tt4[q] + tt4[q + TP_] + tt4[q + 2 * TP_] + tt4[q + 3 * TP_])
                       * (1.f / (nN * nN));
            #pragma unroll
            for (int d = 0; d < DOUT; ++d) ot[d] = fmaf(tv, W5s[c2 * DOUT + d], ot[d]);
        }
        for (int d = 0; d < DOUT; d += 4)
            *(float4*)(tbp + (size_t)(b * nN + m) * DOUT + d) = make_float4(ot[d], ot[d+1], ot[d+2], ot[d+3]);
    }
}

// ---------------------------------------------------------------------------
// Layer 0: t0 = xi*xj*xm (symmetric). v = mask*(t0@(P0+P1)) + small, + bv.
// Weights in LDS (Wl[0..1023] = v-sum, Wl[1024..2047] = w-sum).
__global__ __launch_bounds__(256, 4) void k_vw0(
    const float* __restrict__ x, const float* __restrict__ vm,
    const float* __restrict__ drv, const float* __restrict__ ccv, const float* __restrict__ tbv,
    const float* __restrict__ drw, const float* __restrict__ ccw, const float* __restrict__ tbw,
    const float* __restrict__ pmv, const float* __restrict__ pmw,
    const float* __restrict__ bv, const float* __restrict__ bw,
    float* __restrict__ vout, float* __restrict__ wout)
{
    __shared__ float sA[128 * 36];
    __shared__ float Wl[2048];
    const int tid = threadIdx.x;
    const long base = (long)blockIdx.x * 128;

    for (int q = tid; q < 1024; q += 256) {
        Wl[q]        = pmv[q] + pmv[1024 + q];
        Wl[1024 + q] = pmw[q] + pmw[1024 + q];
    }
    for (int rep = 0; rep < 4; ++rep) {
        int q = rep * 256 + tid; int pl = q >> 3, cq = q & 7;
        int p = (int)base + pl;
        int b, i, j, m; decodePos(p, b, i, j, m);
        float4 xi = *(const float4*)(x + (size_t)(b * nN + i) * nC + cq * 4);
        float4 xj = *(const float4*)(x + (size_t)(b * nN + j) * nC + cq * 4);
        float4 xm = *(const float4*)(x + (size_t)(b * nN + m) * nC + cq * 4);
        *(float4*)(sA + pl * 36 + cq * 4) =
            make_float4(xi.x * xj.x * xm.x, xi.y * xj.y * xm.y,
                        xi.z * xj.z * xm.z, xi.w * xj.w * xm.w);
    }
    __syncthreads();

    const int pt = tid >> 3, dq = tid & 7, d0 = dq * 4;
    float acc[4][4];

    auto zeroAcc = [&]() {
        #pragma unroll
        for (int a2 = 0; a2 < 4; ++a2)
            #pragma unroll
            for (int l = 0; l < 4; ++l) acc[a2][l] = 0.f;
    };
    auto sweep = [&](const float* sp, const float* wl) {
        #pragma unroll
        for (int cq2 = 0; cq2 < 8; ++cq2) {
            float4 w0 = *(const float4*)(wl + (cq2 * 4 + 0) * 32 + d0);
            float4 w1 = *(const float4*)(wl + (cq2 * 4 + 1) * 32 + d0);
            float4 w2 = *(const float4*)(wl + (cq2 * 4 + 2) * 32 + d0);
            float4 w3 = *(const float4*)(wl + (cq2 * 4 + 3) * 32 + d0);
            #pragma unroll
            for (int l = 0; l < 4; ++l) {
                float4 tv = *(const float4*)(sp + (pt + 32 * l) * 36 + cq2 * 4);
                acc[l][0] = fmaf(tv.x, w0.x, acc[l][0]); acc[l][1] = fmaf(tv.x, w0.y, acc[l][1]);
                acc[l][2] = fmaf(tv.x, w0.z, acc[l][2]); acc[l][3] = fmaf(tv.x, w0.w, acc[l][3]);
                acc[l][0] = fmaf(tv.y, w1.x, acc[l][0]); acc[l][1] = fmaf(tv.y, w1.y, acc[l][1]);
                acc[l][2] = fmaf(tv.y, w1.z, acc[l][2]); acc[l][3] = fmaf(tv.y, w1.w, acc[l][3]);
                acc[l][0] = fmaf(tv.z, w2.x, acc[l][0]); acc[l][1] = fmaf(tv.z, w2.y, acc[l][1]);
                acc[l][2] = fmaf(tv.z, w2.z, acc[l][2]); acc[l][3] = fmaf(tv.z, w2.w, acc[l][3]);
                acc[l][0] = fmaf(tv.w, w3.x, acc[l][0]); acc[l][1] = fmaf(tv.w, w3.y, acc[l][1]);
                acc[l][2] = fmaf(tv.w, w3.z, acc[l][2]); acc[l][3] = fmaf(tv.w, w3.w, acc[l][3]);
            }
        }
    };
    auto finish = [&](const float* drS, const float* ccS, const float* tbS,
                      const float* bias, float* outp) {
        float4 b4 = *(const float4*)(bias + d0);
        #pragma unroll
        for (int l = 0; l < 4; ++l) {
            int p = (int)base + pt + 32 * l;
            int b, i, j, m; decodePos(p, b, i, j, m);
            float4 d4 = *(const float4*)(drS + (size_t)((b * nN + i) * nN + m) * nC + d0);
            float4 c4 = *(const float4*)(ccS + (size_t)((b * nN + j) * nN + m) * nC + d0);
            float4 t4 = *(const float4*)(tbS + (size_t)(b * nN + m) * nC + d0);
            float mk = vm[b * nN + i] * vm[b * nN + j] * vm[b * nN + m];
            float4 o4;
            o4.x = (acc[l][0] + d4.x + c4.x + t4.x) * mk + b4.x;
            o4.y = (acc[l][1] + d4.y + c4.y + t4.y) * mk + b4.y;
            o4.z = (acc[l][2] + d4.z + c4.z + t4.z) * mk + b4.z;
            o4.w = (acc[l][3] + d4.w + c4.w + t4.w) * mk + b4.w;
            *(float4*)(outp + (size_t)p * nC + d0) = o4;
        }
    };

    zeroAcc(); sweep(sA, Wl);        finish(drv, ccv, tbv, bv, vout);
    zeroAcc(); sweep(sA, Wl + 1024); finish(drw, ccw, tbw, bw, wout);
}

// ---------------------------------------------------------------------------
// Layer 1: v = mask*(t@P0v + tT@P1v + small) + bv (same for w). Weights in
// LDS: Wl[0]=vP0, [1024]=vP1, [2048]=wP0, [3072]=wP1. t + tT staged per block.
__global__ __launch_bounds__(256, 3) void k_vw1(
    const float* __restrict__ t, const float* __restrict__ vm,
    const float* __restrict__ drv, const float* __restrict__ ccv, const float* __restrict__ tbv,
    const float* __restrict__ drw, const float* __restrict__ ccw, const float* __restrict__ tbw,
    const float* __restrict__ pmv, const float* __restrict__ pmw,
    const float* __restrict__ bv, const float* __restrict__ bw,
    float* __restrict__ vout, float* __restrict__ wout)
{
    __shared__ float sA[128 * 36], sB[128 * 36];
    __shared__ float Wl[4096];
    const int tid = threadIdx.x;
    const long base = (long)blockIdx.x * 128;

    for (int q = tid; q < 2048; q += 256) {
        Wl[q]        = pmv[q];
        Wl[2048 + q] = pmw[q];
    }
    for (int rep = 0; rep < 4; ++rep) {
        int q = rep * 256 + tid; int pl = q >> 3, cq = q & 7;
        long p = base + pl;
        *(float4*)(sA + pl * 36 + cq * 4) = *(const float4*)(t + p * nC + cq * 4);
        int b, i, j, m; decodePos((int)p, b, i, j, m);
        long pT = ((long)(b * nN + j) * nN + i) * nN + m;
        *(float4*)(sB + pl * 36 + cq * 4) = *(const float4*)(t + pT * nC + cq * 4);
    }
    __syncthreads();

    const int pt = tid >> 3, dq = tid & 7, d0 = dq * 4;
    float acc[4][4];

    auto zeroAcc = [&]() {
        #pragma unroll
        for (int a2 = 0; a2 < 4; ++a2)
            #pragma unroll
            for (int l = 0; l < 4; ++l) acc[a2][l] = 0.f;
    };
    auto sweep = [&](const float* sp, const float* wl) {
        #pragma unroll
        for (int cq2 = 0; cq2 < 8; ++cq2) {
            float4 w0 = *(const float4*)(wl + (cq2 * 4 + 0) * 32 + d0);
            float4 w1 = *(const float4*)(wl + (cq2 * 4 + 1) * 32 + d0);
            float4 w2 = *(const float4*)(wl + (cq2 * 4 + 2) * 32 + d0);
            float4 w3 = *(const float4*)(wl + (cq2 * 4 + 3) * 32 + d0);
            #pragma unroll
            for (int l = 0; l < 4; ++l) {
                float4 tv = *(const float4*)(sp + (pt + 32 * l) * 36 + cq2 * 4);
                acc[l][0] = fmaf(tv.x, w0.x, acc[l][0]); acc[l][1] = fmaf(tv.x, w0.y, acc[l][1]);
                acc[l][2] = fmaf(tv.x, w0.z, acc[l][2]); acc[l][3] = fmaf(tv.x, w0.w, acc[l][3]);
                acc[l][0] = fmaf(tv.y, w1.x, acc[l][0]); acc[l][1] = fmaf(tv.y, w1.y, acc[l][1]);
                acc[l][2] = fmaf(tv.y, w1.z, acc[l][2]); acc[l][3] = fmaf(tv.y, w1.w, acc[l][3]);
                acc[l][0] = fmaf(tv.z, w2.x, acc[l][0]); acc[l][1] = fmaf(tv.z, w2.y, acc[l][1]);
                acc[l][2] = fmaf(tv.z, w2.z, acc[l][2]); acc[l][3] = fmaf(tv.z, w2.w, acc[l][3]);
                acc[l][0] = fmaf(tv.w, w3.x, acc[l][0]); acc[l][1] = fmaf(tv.w, w3.y, acc[l][1]);
                acc[l][2] = fmaf(tv.w, w3.z, acc[l][2]); acc[l][3] = fmaf(tv.w, w3.w, acc[l][3]);
            }
        }
    };
    auto finish = [&](const float* drS, const float* ccS, const float* tbS,
                      const float* bias, float* outp) {
        float4 b4 = *(const float4*)(bias + d0);
        #pragma unroll
        for (int l = 0; l < 4; ++l) {
            int p = (int)base + pt + 32 * l;
            int b, i, j, m; decodePos(p, b, i, j, m);
            float4 d4 = *(const float4*)(drS + (size_t)((b * nN + i) * nN + m) * nC + d0);
            float4 c4 = *(const float4*)(ccS + (size_t)((b * nN + j) * nN + m) * nC + d0);
            float4 t4 = *(const float4*)(tbS + (size_t)(b * nN + m) * nC + d0);
            float mk = vm[b * nN + i] * vm[b * nN + j] * vm[b * nN + m];
            float4 o4;
            o4.x = (acc[l][0] + d4.x + c4.x + t4.x) * mk + b4.x;
            o4.y = (acc[l][1] + d4.y + c4.y + t4.y) * mk + b4.y;
            o4.z = (acc[l][2] + d4.z + c4.z + t4.z) * mk + b4.z;
            o4.w = (acc[l][3] + d4.w + c4.w + t4.w) * mk + b4.w;
            *(float4*)(outp + (size_t)p * nC + d0) = o4;
        }
    };

    zeroAcc(); sweep(sA, Wl);        sweep(sB, Wl + 1024);
    finish(drv, ccv, tbv, bv, vout);
    zeroAcc(); sweep(sA, Wl + 2048); sweep(sB, Wl + 3072);
    finish(drw, ccw, tbw, bw, wout);
}

// ---------------------------------------------------------------------------
// z = V*W/n per (b,m); o-mix + relu + mask -> t; fused rows/cols/diag/tot
// partial reductions (no atomics). Tile 24i x 24j x 32c; 768 blocks.
__global__ __launch_bounds__(256, 3) void k_z(
    const float* __restrict__ v, const float* __restrict__ w,
    const float* __restrict__ Wo, const float* __restrict__ bo,
    const float* __restrict__ vm, float* __restrict__ tout,
    float* __restrict__ rows2, float* __restrict__ cols2,
    float* __restrict__ diag_, float* __restrict__ tot4)
{
    __shared__ float lds[12912];           // 51648 B -> 3 blocks/CU
    float* Vt = lds;                       // [kk][c][i]: kk*807 + c*25 + i
    float* Wt = lds + 6456;
    constexpr int ZS = 34;                 // z/out row stride (per position)
    constexpr int ZWO = 9792;              // Wo area
    constexpr int TOT0 = 10816;            // tot scratch [8][32]
    const int tid = threadIdx.x;
    const int blk = blockIdx.x;
    const int tl = blk & 3; const int bm = blk >> 2;
    const int it = tl >> 1, jt = tl & 1;
    const int b = bm / nN, m = bm % nN;
    const int c = tid & 31;
    const int g = tid >> 5;
    const int i3 = g >> 1, j2 = g & 1;     // i3 wave-uniform
    const int il0 = i3 * 6, jl0 = j2 * 12;
    const size_t posbase = (size_t)b * SB_ + (size_t)m * nC;

    float acc[6][12];
    #pragma unroll
    for (int l = 0; l < 6; ++l)
        #pragma unroll
        for (int u = 0; u < 12; ++u) acc[l][u] = 0.f;

    for (int kc = 0; kc < 6; ++kc) {
        if (kc) __syncthreads();
        #pragma unroll
        for (int rr = 0; rr < 6; ++rr) {          // V: 24i x 8k x 32c
            int q = rr * 256 + tid; int pos = q >> 3, cq = q & 7;
            int ii = pos >> 3, kk = pos & 7;
            float4 a = *(const float4*)(v + posbase + (size_t)(it * 24 + ii) * SI_
                                          + (size_t)(kc * 8 + kk) * SJ_ + cq * 4);
            float* dst = Vt + kk * 807 + (cq * 4) * 25 + ii;
            dst[0] = a.x; dst[25] = a.y; dst[50] = a.z; dst[75] = a.w;
        }
        #pragma unroll
        for (int rr = 0; rr < 6; ++rr) {          // W: 8k x 24j x 32c
            int q = rr * 256 + tid; int pos = q >> 3, cq = q & 7;
            int kk = pos / 24, jj = pos - kk * 24;
            float4 a = *(const float4*)(w + posbase + (size_t)(kc * 8 + kk) * SI_
                                          + (size_t)(jt * 24 + jj) * SJ_ + cq * 4);
            float* dst = Wt + kk * 807 + (cq * 4) * 25 + jj;
            dst[0] = a.x; dst[25] = a.y; dst[50] = a.z; dst[75] = a.w;
        }
        __syncthreads();
        #pragma unroll
        for (int kk = 0; kk < 8; ++kk) {
            float vf[6], wf[12];
            #pragma unroll
            for (int l = 0; l < 6; ++l) vf[l] = Vt[kk * 807 + c * 25 + il0 + l];
            #pragma unroll
            for (int u = 0; u < 12; ++u) wf[u] = Wt[kk * 807 + c * 25 + jl0 + u];
            #pragma unroll
            for (int l = 0; l < 6; ++l)
                #pragma unroll
                for (int u = 0; u < 12; ++u)
                    acc[l][u] = fmaf(vf[l], wf[u], acc[l][u]);
        }
    }
    __syncthreads();                               // staging area now reusable

    #pragma unroll
    for (int e = 0; e < 4; ++e)                    // Wo * (1/48)
        lds[ZWO + e * 256 + tid] = Wo[e * 256 + tid] * (1.f / nN);

    const int ptE = tid >> 3, dqE = tid & 7, d0 = dqE * 4;
    const float4 b4 = *(const float4*)(bo + d0);
    const float vmm = vm[b * nN + m];
    float colacc[3] = {0.f, 0.f, 0.f};
    float totacc = 0.f;

    for (int h = 0; h < 2; ++h) {
        if (h) __syncthreads();                    // protect h=0 reduction reads
        if ((i3 >> 1) == h) {                      // write this half's z
            int r0 = il0 - 12 * h;                 // 0 or 6
            #pragma unroll
            for (int l = 0; l < 6; ++l)
                #pragma unroll
                for (int u = 0; u < 12; ++u)
                    lds[((r0 + l) * 24 + jl0 + u) * ZS + c] = acc[l][u];
        }
        __syncthreads();                           // z + wo visible

        float oac[9][4];
        #pragma unroll
        for (int u = 0; u < 9; ++u)
            #pragma unroll
            for (int d = 0; d < 4; ++d) oac[u][d] = 0.f;
        #pragma unroll
        for (int c2 = 0; c2 < 32; ++c2) {
            float4 wo4 = *(const float4*)(lds + ZWO + c2 * 32 + d0);
            float zv[9];
            #pragma unroll
            for (int u = 0; u < 9; ++u) zv[u] = lds[(ptE * 9 + u) * ZS + c2];
            #pragma unroll
            for (int u = 0; u < 9; ++u) {
                oac[u][0] = fmaf(zv[u], wo4.x, oac[u][0]);
                oac[u][1] = fmaf(zv[u], wo4.y, oac[u][1]);
                oac[u][2] = fmaf(zv[u], wo4.z, oac[u][2]);
                oac[u][3] = fmaf(zv[u], wo4.w, oac[u][3]);
            }
        }
        __syncthreads();                           // all z reads done

        #pragma unroll
        for (int u = 0; u < 9; ++u) {
            int p = ptE * 9 + u;
            int rl = p / 24, jl = p - rl * 24;
            int gi = it * 24 + 12 * h + rl, gj = jt * 24 + jl;
            float mk = vm[b * nN + gi] * vm[b * nN + gj] * vmm;
            float4 o4;
            o4.x = fmaxf(oac[u][0] + b4.x, 0.f) * mk;
            o4.y = fmaxf(oac[u][1] + b4.y, 0.f) * mk;
            o4.z = fmaxf(oac[u][2] + b4.z, 0.f) * mk;
            o4.w = fmaxf(oac[u][3] + b4.w, 0.f) * mk;
            *(float4*)(tout + posbase + (size_t)gi * SI_ + (size_t)gj * SJ_ + d0) = o4;
            *(float2*)(lds + p * ZS + d0) = make_float2(o4.x, o4.y);
            *(float2*)(lds + p * ZS + d0 + 2) = make_float2(o4.z, o4.w);
        }
        __syncthreads();                           // out tile visible in LDS

        for (int rd = 0; rd < 2; ++rd) {
            int task = rd * 256 + tid;
            if (task < 384) {
                int i_r = task >> 5, c_r = task & 31;
                float rsum = 0.f;
                #pragma unroll
                for (int jl = 0; jl < 24; ++jl) rsum += lds[(i_r * 24 + jl) * ZS + c_r];
                int gi = it * 24 + 12 * h + i_r;
                rows2[(size_t)jt * RP_ + ((size_t)(b * nN + gi) * nN + m) * nC + c_r] = rsum;
                totacc += rsum;
                if (it == jt)
                    diag_[((size_t)(b * nN + gi) * nN + m) * nC + c_r] =
                        lds[(i_r * 24 + (12 * h + i_r)) * ZS + c_r];
            }
        }
        #pragma unroll
        for (int rr = 0; rr < 3; ++rr) {
            int task = rr * 256 + tid;
            int jl = task >> 5, c_c = task & 31;
            float csum = 0.f;
            #pragma unroll
            for (int il = 0; il < 12; ++il) csum += lds[(il * 24 + jl) * ZS + c_c];
            colacc[rr] += csum;
        }
    }

    #pragma unroll
    for (int rr = 0; rr < 3; ++rr) {
        int task = rr * 256 + tid;
        int jl = task >> 5, c_c = task & 31;
        cols2[(size_t)it * CP_ + ((size_t)(b * nN + jt * 24 + jl) * nN + m) * nC + c_c] = colacc[rr];
    }
    lds[TOT0 + g * 32 + c] = totacc;
    __syncthreads();
    if (tid < 32) {
        float s = 0.f;
        #pragma unroll
        for (int gg = 0; gg < 8; ++gg) s += lds[TOT0 + gg * 32 + tid];
        tot4[(size_t)(it * 2 + jt) * TP_ + (size_t)(b * nN + m) * nC + tid] = s;
    }
}

// ---------------------------------------------------------------------------
// Final snconv2 (C_out=16), weights in LDS, direct to d_out.
__global__ __launch_bounds__(256, 3) void k_final(
    const float* __restrict__ t, const float* __restrict__ vm,
    const float* __restrict__ drp, const float* __restrict__ ccp, const float* __restrict__ tbp,
    const float* __restrict__ W0, const float* __restrict__ W1,
    float* __restrict__ out)
{
    __shared__ float sA[128 * 36], sB[128 * 36];
    __shared__ float Wf[1024];
    const int tid = threadIdx.x;
    const long base = (long)blockIdx.x * 128;

    for (int q = tid; q < 512; q += 256) {
        Wf[q] = W0[q]; Wf[512 + q] = W1[q];
    }
    for (int rep = 0; rep < 4; ++rep) {
        int q = rep * 256 + tid; int pl = q >> 3, cq = q & 7;
        long p = base + pl;
        *(float4*)(sA + pl * 36 + cq * 4) = *(const float4*)(t + p * nC + cq * 4);
        int b, i, j, m; decodePos((int)p, b, i, j, m);
        long pT = ((long)(b * nN + j) * nN + i) * nN + m;
        *(float4*)(sB + pl * 36 + cq * 4) = *(const float4*)(t + pT * nC + cq * 4);
    }
    __syncthreads();

    const int pt = tid >> 3, dq = tid & 7, d0 = dq * 2;
    float acc[4][2];
    #pragma unroll
    for (int l = 0; l < 4; ++l) { acc[l][0] = 0.f; acc[l][1] = 0.f; }

    auto sweep = [&](const float* sp, const float* wl) {
        #pragma unroll
        for (int cq2 = 0; cq2 < 8; ++cq2) {
            float2 w0 = *(const float2*)(wl + (cq2 * 4 + 0) * 16 + d0);
            float2 w1 = *(const float2*)(wl + (cq2 * 4 + 1) * 16 + d0);
            float2 w2 = *(const float2*)(wl + (cq2 * 4 + 2) * 16 + d0);
            float2 w3 = *(const float2*)(wl + (cq2 * 4 + 3) * 16 + d0);
            #pragma unroll
            for (int l = 0; l < 4; ++l) {
                float4 tv = *(const float4*)(sp + (pt + 32 * l) * 36 + cq2 * 4);
                acc[l][0] = fmaf(tv.x, w0.x, acc[l][0]); acc[l][1] = fmaf(tv.x, w0.y, acc[l][1]);
                acc[l][0] = fmaf(tv.y, w1.x, acc[l][0]); acc[l][1] = fmaf(tv.y, w1.y, acc[l][1]);
                acc[l][0] = fmaf(tv.z, w2.x, acc[l][0]); acc[l][1] = fmaf(tv.z, w2.y, acc[l][1]);
                acc[l][0] = fmaf(tv.w, w3.x, acc[l][0]); acc[l][1] = fmaf(tv.w, w3.y, acc[l][1]);
            }
        }
    };

    sweep(sA, Wf);
    sweep(sB, Wf + 512);

    #pragma unroll
    for (int l = 0; l < 4; ++l) {
        int p = (int)base + pt + 32 * l;
        int b, i, j, m; decodePos(p, b, i, j, m);
        float2 d2 = *(const float2*)(drp + (size_t)((b * nN + i) * nN + m) * 16 + d0);
        float2 cc2 = *(const float2*)(ccp + (size_t)((b * nN + j) * nN + m) * 16 + d0);
        float2 tb2 = *(const float2*)(tbp + (size_t)(b * nN + m) * 16 + d0);
        float mk = vm[b * nN + i] * vm[b * nN + j] * vm[b * nN + m];
        float2 o2;
        o2.x = (acc[l][0] + d2.x + cc2.x + tb2.x) * mk;
        o2.y = (acc[l][1] + d2.y + cc2.y + tb2.y) * mk;
        *(float2*)(out + (size_t)p * 16 + d0) = o2;
    }
}

} // anonymous namespace

// ---------------------------------------------------------------------------
extern "C" void kernel_launch(void* const* d_in, const int* in_sizes, int n_in,
                              void* d_out, int out_size, void* d_ws, size_t ws_size,
                              hipStream_t stream)
{
    (void)in_sizes; (void)n_in; (void)out_size; (void)ws_size;
    const float* x    = (const float*)d_in[0];
    const void*  mask = d_in[1];
    const float* bW0  = (const float*)d_in[2];
    const float* bb0  = (const float*)d_in[3];
    const float* lvW0 = (const float*)d_in[4];
    const float* lvb0 = (const float*)d_in[5];
    const float* lwW0 = (const float*)d_in[6];
    const float* lwb0 = (const float*)d_in[7];
    const float* loW0 = (const float*)d_in[8];
    const float* lob0 = (const float*)d_in[9];
    const float* bW1  = (const float*)d_in[10];
    const float* bb1  = (const float*)d_in[11];
    const float* lvW1 = (const float*)d_in[12];
    const float* lvb1 = (const float*)d_in[13];
    const float* lwW1 = (const float*)d_in[14];
    const float* lwb1 = (const float*)d_in[15];
    const float* loW1 = (const float*)d_in[16];
    const float* lob1 = (const float*)d_in[17];
    const float* fW   = (const float*)d_in[18];
    const float* fb   = (const float*)d_in[19];

    float* ws  = (float*)d_ws;
    float* t     = ws;                          // 14155776
    float* v     = ws + 14155776L;
    float* w     = ws + 28311552L;
    float* rows2 = ws + 42467328L;              // 2 * 294912
    float* cols2 = rows2 + 2 * 294912;          // 2 * 294912
    float* diag  = cols2 + 2 * 294912;          // 294912
    float* tot4  = diag + 294912;               // 4 * 6144
    float* drv   = tot4 + 4 * 6144;             // 294912
    float* ccv   = drv + 294912;                // 294912
    float* tbv   = ccv + 294912;                // 6144
    float* drw   = tbv + 6144;                  // 294912
    float* ccw   = drw + 294912;                // 294912
    float* tbw   = ccw + 294912;                // 6144
    float* pm    = tbw + 6144;                  // 4 * 6176
    float* S     = pm + 4 * 6176;               // 128
    float* vm    = S + 128;                     // 192
    float* out   = (float*)d_out;

    const float* pmL0v = pm;                 // layer0 v-set
    const float* pmL0w = pm + 6176;          // layer0 w-set
    const float* pmL1v = pm + 2 * 6176;      // layer1 v-set
    const float* pmL1w = pm + 3 * 6176;      // layer1 w-set

    k_prep<<<1, 256, 0, stream>>>(x, mask, vm, S);
    k_wmix<<<4, 256, 0, stream>>>(bW0, bb0, lvW0, lwW0, bW1, bb1, lvW1, lwW1, pm);
    k_mix0<<<36, 256, 0, stream>>>(x, S, pmL0v, pmL0v + 6144, drv, ccv, tbv);
    k_mix0<<<36, 256, 0, stream>>>(x, S, pmL0w, pmL0w + 6144, drw, ccw, tbw);
    k_vw0<<<3456, 256, 0, stream>>>(x, vm, drv, ccv, tbv, drw, ccw, tbw,
                                    pmL0v, pmL0w, lvb0, lwb0, v, w);
    k_z<<<768, 256, 0, stream>>>(v, w, loW0, lob0, vm, t, rows2, cols2, diag, tot4);
    k_mix<32><<<36, 256, 0, stream>>>(diag, rows2, cols2, tot4, pmL1v, pmL1v + 6144, drv, ccv, tbv);
    k_mix<32><<<36, 256, 0, stream>>>(diag, rows2, cols2, tot4, pmL1w, pmL1w + 6144, drw, ccw, tbw);
    k_vw1<<<3456, 256, 0, stream>>>(t, vm, drv, ccv, tbv, drw, ccw, tbw,
                                    pmL1v, pmL1w, lvb1, lwb1, v, w);
    k_z<<<768, 256, 0, stream>>>(v, w, loW1, lob1, vm, t, rows2, cols2, diag, tot4);
    k_mix<16><<<36, 256, 0, stream>>>(diag, rows2, cols2, tot4, fW, fb, drv, ccv, tbv);
    k_final<<<3456, 256, 0, stream>>>(t, vm, drv, ccv, tbv, fW, fW + 512, out);
}

// Round 6
// 537.710 us; speedup vs baseline: 4.4663x; 2.9655x over previous
//
#include <hip/hip_runtime.h>
#include <cstdint>

// ---------------------------------------------------------------------------
// SnLocalDecoder: B=4, n=48, C=32. Round-6: best-of-breed composite from
// MEASURED-FAST pieces only, after R4/R5's k_vw rewrites both produced
// unexplained GB-scale HBM traffic (suspected scratch/codegen pathology):
//   - k_vw<0/1>: R1 verbatim (92 us measured, WRITE 110 MB clean).
//   - k_z: R3 verbatim (24x24 tile, 768 blocks = 3/CU, conflict-free LDS).
//   - k_red4 + partial-sum k_mix: R3 verbatim (no atomics).
//   - k_final: R1 verbatim.
// No premix, no transpose-pair blocks, no fused k_z reductions.
// ---------------------------------------------------------------------------

namespace {

constexpr int nB = 4, nN = 48, nC = 32;
constexpr int SJ_ = nN * nC;            // 1536
constexpr int SI_ = nN * SJ_;           // 73728
constexpr long SB_ = (long)nN * SI_;    // 3538944
constexpr int CP_ = 294912;             // cols-partial stride
constexpr int TP_ = 6144;               // tot-partial stride

__device__ __forceinline__ void decodePos(int p, int& b, int& i, int& j, int& m) {
    m = p % nN; int r = p / nN;
    j = r % nN; r /= nN;
    i = r % nN; b = r / nN;
}

// ---------------------------------------------------------------------------
__global__ __launch_bounds__(256) void k_prep(const float* __restrict__ x,
                                              const void* __restrict__ maskp,
                                              float* __restrict__ vm,
                                              float* __restrict__ S)
{
    __shared__ float vmL[nB * nN];
    const int tid = threadIdx.x;
    const unsigned int w0 = *(const unsigned int*)maskp;
    const bool is_byte = (w0 == 0x01010101u);   // bool-byte layout
    if (tid < nB * nN) {
        int b = tid / nN, i = tid % nN;
        long idx = ((long)(b * nN + i) * nN + i) * nN + i;   // mask[b,i,i,i]
        int bit;
        if (is_byte) bit = (((const unsigned char*)maskp)[idx] != 0);
        else         bit = (((const int*)maskp)[idx] != 0);
        float f = bit ? 1.f : 0.f;
        vm[tid] = f; vmL[tid] = f;
    }
    __syncthreads();
    if (tid < nB * nC) {
        int b = tid >> 5, c = tid & 31;
        float s = 0.f;
        for (int j = 0; j < nN; ++j) s += x[(b * nN + j) * nC + c] * vmL[b * nN + j];
        S[tid] = s;
    }
}

// ---------------------------------------------------------------------------
// Layer-0 small snconv2 terms, closed form from x and S.
__global__ __launch_bounds__(256) void k_mix0(
    const float* __restrict__ x, const float* __restrict__ S,
    const float* __restrict__ Wb, const float* __restrict__ bias,
    float* __restrict__ drp, float* __restrict__ ccp, float* __restrict__ tbp)
{
    __shared__ float W2s[1024], W3s[1024], W4s[1024], W5s[1024], bs[32];
    const int tid = threadIdx.x;
    for (int q = tid; q < 1024; q += 256) {
        W2s[q] = Wb[2048 + q]; W3s[q] = Wb[3072 + q];
        W4s[q] = Wb[4096 + q]; W5s[q] = Wb[5120 + q];
    }
    if (tid < 32) bs[tid] = bias[tid];
    __syncthreads();
    const int id = blockIdx.x * 256 + tid;        // (b*48+i)*48+m
    const int m = id % nN; int r = id / nN; const int i = r % nN; const int b = r / nN;
    float odr[32], occ[32];
    #pragma unroll
    for (int d = 0; d < 32; ++d) { odr[d] = 0.f; occ[d] = 0.f; }
    for (int c2 = 0; c2 < 32; ++c2) {
        float xi = x[(b * nN + i) * nC + c2];
        float xm = x[(b * nN + m) * nC + c2];
        float sc = S[b * nC + c2];
        float A = xi * xi * xm;
        float R = xi * xm * sc * (1.f / nN);
        #pragma unroll
        for (int d = 0; d < 32; ++d) {
            odr[d] = fmaf(A, W2s[c2 * 32 + d], fmaf(R, W3s[c2 * 32 + d], odr[d]));
            occ[d] = fmaf(R, W4s[c2 * 32 + d], occ[d]);
        }
    }
    #pragma unroll
    for (int d = 0; d < 32; d += 4) {
        *(float4*)(drp + (size_t)id * 32 + d) = make_float4(odr[d], odr[d+1], odr[d+2], odr[d+3]);
        *(float4*)(ccp + (size_t)id * 32 + d) = make_float4(occ[d], occ[d+1], occ[d+2], occ[d+3]);
    }
    if (i == 0) {
        float ot[32];
        #pragma unroll
        for (int d = 0; d < 32; ++d) ot[d] = bs[d];
        for (int c2 = 0; c2 < 32; ++c2) {
            float xm = x[(b * nN + m) * nC + c2];
            float sc = S[b * nC + c2];
            float Tc = xm * sc * sc * (1.f / (nN * nN));
            #pragma unroll
            for (int d = 0; d < 32; ++d) ot[d] = fmaf(Tc, W5s[c2 * 32 + d], ot[d]);
        }
        for (int d = 0; d < 32; d += 4)
            *(float4*)(tbp + (size_t)(b * nN + m) * 32 + d) = make_float4(ot[d], ot[d+1], ot[d+2], ot[d+3]);
    }
}

// ---------------------------------------------------------------------------
// Generic small snconv2 terms; cols/tot arrive as 4 i-quarter partials.
template <int DOUT>
__global__ __launch_bounds__(256) void k_mix(
    const float* __restrict__ dgp, const float* __restrict__ rwp,
    const float* __restrict__ clp4, const float* __restrict__ ttp4,
    const float* __restrict__ Wb, const float* __restrict__ bias,
    float* __restrict__ drp, float* __restrict__ ccp, float* __restrict__ tbp)
{
    __shared__ float W2s[32 * DOUT], W3s[32 * DOUT], W4s[32 * DOUT], W5s[32 * DOUT], bs[DOUT];
    const int tid = threadIdx.x;
    for (int q = tid; q < 32 * DOUT; q += 256) {
        W2s[q] = Wb[2 * 32 * DOUT + q]; W3s[q] = Wb[3 * 32 * DOUT + q];
        W4s[q] = Wb[4 * 32 * DOUT + q]; W5s[q] = Wb[5 * 32 * DOUT + q];
    }
    if (tid < DOUT) bs[tid] = bias[tid];
    __syncthreads();
    const int id = blockIdx.x * 256 + tid;
    const int m = id % nN; int r = id / nN; const int i = r % nN; const int b = r / nN;
    float odr[DOUT], occ[DOUT];
    #pragma unroll
    for (int d = 0; d < DOUT; ++d) { odr[d] = 0.f; occ[d] = 0.f; }
    for (int c2 = 0; c2 < 32; ++c2) {
        size_t q = (size_t)id * 32 + c2;
        float dg = dgp[q];
        float rw = rwp[q];
        float cl = clp4[q] + clp4[q + CP_] + clp4[q + 2 * CP_] + clp4[q + 3 * CP_];
        #pragma unroll
        for (int d = 0; d < DOUT; ++d) {
            odr[d] = fmaf(dg, W2s[c2 * DOUT + d], fmaf(rw, W3s[c2 * DOUT + d], odr[d]));
            occ[d] = fmaf(cl, W4s[c2 * DOUT + d], occ[d]);
        }
    }
    #pragma unroll
    for (int d = 0; d < DOUT; d += 4) {
        *(float4*)(drp + (size_t)id * DOUT + d) = make_float4(odr[d], odr[d+1], odr[d+2], odr[d+3]);
        *(float4*)(ccp + (size_t)id * DOUT + d) = make_float4(occ[d], occ[d+1], occ[d+2], occ[d+3]);
    }
    if (i == 0) {
        float ot[DOUT];
        #pragma unroll
        for (int d = 0; d < DOUT; ++d) ot[d] = bs[d];
        for (int c2 = 0; c2 < 32; ++c2) {
            size_t q = (size_t)(b * nN + m) * 32 + c2;
            float tv = ttp4[q] + ttp4[q + TP_] + ttp4[q + 2 * TP_] + ttp4[q + 3 * TP_];
            #pragma unroll
            for (int d = 0; d < DOUT; ++d) ot[d] = fmaf(tv, W5s[c2 * DOUT + d], ot[d]);
        }
        for (int d = 0; d < DOUT; d += 4)
            *(float4*)(tbp + (size_t)(b * nN + m) * DOUT + d) = make_float4(ot[d], ot[d+1], ot[d+2], ot[d+3]);
    }
}

// ---------------------------------------------------------------------------
// Reductions of t, NO atomics: rows/diag direct; cols/tot as per-iq partials.
// Grid: (b*48+m)*4 + iq, block 256 = (jg in 8) x (c in 32).
__global__ __launch_bounds__(256) void k_red4(
    const float* __restrict__ t,
    float* __restrict__ rows_, float* __restrict__ cols4,
    float* __restrict__ diag_, float* __restrict__ tot4)
{
    const int blk = blockIdx.x;
    const int iq = blk & 3; const int bm = blk >> 2;
    const int b = bm / nN, m = bm % nN;
    const int jg = threadIdx.x >> 5;
    const int c = threadIdx.x & 31;
    __shared__ float part[8][32];
    const size_t base = (size_t)b * SB_ + (size_t)m * nC;
    float colacc[6] = {0, 0, 0, 0, 0, 0};
    float totacc = 0.f;
    for (int ii = 0; ii < 12; ++ii) {
        const int i = iq * 12 + ii;
        float vals[6];
        #pragma unroll
        for (int jl = 0; jl < 6; ++jl) {
            int j = jg * 6 + jl;
            vals[jl] = t[base + (size_t)i * SI_ + (size_t)j * SJ_ + c];
        }
        float rp = 0.f;
        #pragma unroll
        for (int jl = 0; jl < 6; ++jl) { colacc[jl] += vals[jl]; rp += vals[jl]; }
        {
            int jd = i - jg * 6;
            if (jd >= 0 && jd < 6) diag_[((size_t)(b * nN + i) * nN + m) * nC + c] = vals[jd];
        }
        part[jg][c] = rp;
        __syncthreads();
        if (jg == 0) {
            float rv = 0.f;
            #pragma unroll
            for (int g = 0; g < 8; ++g) rv += part[g][c];
            rows_[((size_t)(b * nN + i) * nN + m) * nC + c] = rv * (1.f / nN);
            totacc += rv;
        }
        __syncthreads();
    }
    #pragma unroll
    for (int jl = 0; jl < 6; ++jl) {
        int j = jg * 6 + jl;
        cols4[(size_t)iq * CP_ + ((size_t)(b * nN + j) * nN + m) * nC + c] = colacc[jl] * (1.f / nN);
    }
    if (jg == 0)
        tot4[(size_t)iq * TP_ + (size_t)(b * nN + m) * nC + c] = totacc * (1.f / (nN * nN));
}

// ---------------------------------------------------------------------------
// s = masked(snconv2(t)); v = s@Wv+bv; w = s@Ww+bw.  (R1 verbatim: 3-phase,
// wc-in-registers scalar sweep, measured 92 us / WRITE 110 MB.)
template <int MODE>
__global__ __launch_bounds__(256) void k_vw(
    const float* __restrict__ src, const float* __restrict__ vm,
    const float* __restrict__ drp, const float* __restrict__ ccp, const float* __restrict__ tbp,
    const float* __restrict__ W0, const float* __restrict__ W1,
    const float* __restrict__ Wv, const float* __restrict__ bv,
    const float* __restrict__ Ww, const float* __restrict__ bw,
    float* __restrict__ vout, float* __restrict__ wout)
{
    __shared__ float sA[128 * 34];
    __shared__ float sB[(MODE == 0) ? 64 : 128 * 34];
    __shared__ float sS[128 * 34];
    const int tid = threadIdx.x;
    const long base = (long)blockIdx.x * 128;

    if (MODE == 0) {
        for (int rep = 0; rep < 4; ++rep) {
            int q = rep * 256 + tid; int pl = q >> 3, cq = q & 7;
            int p = (int)base + pl;
            int b, i, j, m; decodePos(p, b, i, j, m);
            float4 xi = *(const float4*)(src + (size_t)(b * nN + i) * nC + cq * 4);
            float4 xj = *(const float4*)(src + (size_t)(b * nN + j) * nC + cq * 4);
            float4 xm = *(const float4*)(src + (size_t)(b * nN + m) * nC + cq * 4);
            int o = pl * 34 + cq * 4;
            sA[o + 0] = xi.x * xj.x * xm.x;
            sA[o + 1] = xi.y * xj.y * xm.y;
            sA[o + 2] = xi.z * xj.z * xm.z;
            sA[o + 3] = xi.w * xj.w * xm.w;
        }
    } else {
        for (int rep = 0; rep < 4; ++rep) {
            int q = rep * 256 + tid; int pl = q >> 3, cq = q & 7;
            long p = base + pl;
            float4 a = *(const float4*)(src + p * nC + cq * 4);
            int o = pl * 34 + cq * 4;
            sA[o + 0] = a.x; sA[o + 1] = a.y; sA[o + 2] = a.z; sA[o + 3] = a.w;
            int b, i, j, m; decodePos((int)p, b, i, j, m);
            long pT = ((long)(b * nN + j) * nN + i) * nN + m;
            float4 t4 = *(const float4*)(src + pT * nC + cq * 4);
            sB[o + 0] = t4.x; sB[o + 1] = t4.y; sB[o + 2] = t4.z; sB[o + 3] = t4.w;
        }
    }
    __syncthreads();

    const int pt = tid >> 3, dq = tid & 7;
    const int p0 = pt * 4, d0 = dq * 4;
    float wc[32][4];
    float acc[4][4];

    auto zeroAcc = [&]() {
        #pragma unroll
        for (int a2 = 0; a2 < 4; ++a2)
            #pragma unroll
            for (int l = 0; l < 4; ++l) acc[a2][l] = 0.f;
    };
    auto loadW = [&](const float* Wp) {
        #pragma unroll
        for (int c2 = 0; c2 < 32; ++c2) {
            float4 q4 = *(const float4*)(Wp + c2 * nC + d0);
            wc[c2][0] = q4.x; wc[c2][1] = q4.y; wc[c2][2] = q4.z; wc[c2][3] = q4.w;
        }
    };
    auto addW = [&](const float* Wp) {
        #pragma unroll
        for (int c2 = 0; c2 < 32; ++c2) {
            float4 q4 = *(const float4*)(Wp + c2 * nC + d0);
            wc[c2][0] += q4.x; wc[c2][1] += q4.y; wc[c2][2] += q4.z; wc[c2][3] += q4.w;
        }
    };
    auto sweep = [&](const float* sp) {
        #pragma unroll
        for (int c2 = 0; c2 < 32; ++c2) {
            float t0 = sp[(p0 + 0) * 34 + c2];
            float t1 = sp[(p0 + 1) * 34 + c2];
            float t2 = sp[(p0 + 2) * 34 + c2];
            float t3 = sp[(p0 + 3) * 34 + c2];
            #pragma unroll
            for (int l = 0; l < 4; ++l) {
                acc[0][l] = fmaf(t0, wc[c2][l], acc[0][l]);
                acc[1][l] = fmaf(t1, wc[c2][l], acc[1][l]);
                acc[2][l] = fmaf(t2, wc[c2][l], acc[2][l]);
                acc[3][l] = fmaf(t3, wc[c2][l], acc[3][l]);
            }
        }
    };

    zeroAcc();
    if (MODE == 0) { loadW(W0); addW(W1); sweep(sA); }
    else           { loadW(W0); sweep(sA); loadW(W1); sweep(sB); }

    // add small terms, mask, stash masked s
    #pragma unroll
    for (int l = 0; l < 4; ++l) {
        int p = (int)base + p0 + l;
        int b, i, j, m; decodePos(p, b, i, j, m);
        float4 d4 = *(const float4*)(drp + (size_t)((b * nN + i) * nN + m) * nC + d0);
        float4 c4 = *(const float4*)(ccp + (size_t)((b * nN + j) * nN + m) * nC + d0);
        float4 t4 = *(const float4*)(tbp + (size_t)(b * nN + m) * nC + d0);
        float mk = vm[b * nN + i] * vm[b * nN + j] * vm[b * nN + m];
        int o = (p0 + l) * 34 + d0;
        sS[o + 0] = (acc[l][0] + d4.x + c4.x + t4.x) * mk;
        sS[o + 1] = (acc[l][1] + d4.y + c4.y + t4.y) * mk;
        sS[o + 2] = (acc[l][2] + d4.z + c4.z + t4.z) * mk;
        sS[o + 3] = (acc[l][3] + d4.w + c4.w + t4.w) * mk;
    }
    __syncthreads();

    // stage B: v then w
    zeroAcc(); loadW(Wv); sweep(sS);
    {
        float4 b4 = *(const float4*)(bv + d0);
        #pragma unroll
        for (int l = 0; l < 4; ++l) {
            float4 o4 = make_float4(acc[l][0] + b4.x, acc[l][1] + b4.y,
                                    acc[l][2] + b4.z, acc[l][3] + b4.w);
            *(float4*)(vout + (size_t)(base + p0 + l) * nC + d0) = o4;
        }
    }
    zeroAcc(); loadW(Ww); sweep(sS);
    {
        float4 b4 = *(const float4*)(bw + d0);
        #pragma unroll
        for (int l = 0; l < 4; ++l) {
            float4 o4 = make_float4(acc[l][0] + b4.x, acc[l][1] + b4.y,
                                    acc[l][2] + b4.z, acc[l][3] + b4.w);
            *(float4*)(wout + (size_t)(base + p0 + l) * nC + d0) = o4;
        }
    }
}

// ---------------------------------------------------------------------------
// z = V*W/n per (b,m); o-mix + relu + mask -> t.  (R3 verbatim: 24x24 tile,
// 768 blocks = 3/CU, conflict-free LDS, Wo staged.)
__global__ __launch_bounds__(256, 3) void k_z(
    const float* __restrict__ v, const float* __restrict__ w,
    const float* __restrict__ Wo, const float* __restrict__ bo,
    const float* __restrict__ vm, float* __restrict__ tout)
{
    __shared__ float lds[12912];           // 51648 B -> 3 blocks/CU
    float* Vt = lds;                       // [kk][c][i]: kk*807 + c*25 + i
    float* Wt = lds + 6456;
    const int tid = threadIdx.x;
    const int blk = blockIdx.x;
    const int tl = blk & 3; const int bm = blk >> 2;
    const int it = tl >> 1, jt = tl & 1;
    const int b = bm / nN, m = bm % nN;
    const int c = tid & 31;
    const int g = tid >> 5;
    const int i3 = g >> 1, j2 = g & 1;     // wave = (c x j2), i3 wave-uniform
    const int il0 = i3 * 6, jl0 = j2 * 12;
    const size_t posbase = (size_t)b * SB_ + (size_t)m * nC;

    float acc[6][12];
    #pragma unroll
    for (int l = 0; l < 6; ++l)
        #pragma unroll
        for (int u = 0; u < 12; ++u) acc[l][u] = 0.f;

    for (int kc = 0; kc < 6; ++kc) {
        if (kc) __syncthreads();
        #pragma unroll
        for (int rr = 0; rr < 6; ++rr) {          // V: 24i x 8k x 32c
            int q = rr * 256 + tid; int pos = q >> 3, cq = q & 7;
            int ii = pos >> 3, kk = pos & 7;
            float4 a = *(const float4*)(v + posbase + (size_t)(it * 24 + ii) * SI_
                                          + (size_t)(kc * 8 + kk) * SJ_ + cq * 4);
            float* dst = Vt + kk * 807 + (cq * 4) * 25 + ii;
            dst[0] = a.x; dst[25] = a.y; dst[50] = a.z; dst[75] = a.w;
        }
        #pragma unroll
        for (int rr = 0; rr < 6; ++rr) {          // W: 8k x 24j x 32c
            int q = rr * 256 + tid; int pos = q >> 3, cq = q & 7;
            int kk = pos / 24, jj = pos - kk * 24;
            float4 a = *(const float4*)(w + posbase + (size_t)(kc * 8 + kk) * SI_
                                          + (size_t)(jt * 24 + jj) * SJ_ + cq * 4);
            float* dst = Wt + kk * 807 + (cq * 4) * 25 + jj;
            dst[0] = a.x; dst[25] = a.y; dst[50] = a.z; dst[75] = a.w;
        }
        __syncthreads();
        #pragma unroll
        for (int kk = 0; kk < 8; ++kk) {
            float vf[6], wf[12];
            #pragma unroll
            for (int l = 0; l < 6; ++l) vf[l] = Vt[kk * 807 + c * 25 + il0 + l];
            #pragma unroll
            for (int u = 0; u < 12; ++u) wf[u] = Wt[kk * 807 + c * 25 + jl0 + u];
            #pragma unroll
            for (int l = 0; l < 6; ++l)
                #pragma unroll
                for (int u = 0; u < 12; ++u)
                    acc[l][u] = fmaf(vf[l], wf[u], acc[l][u]);
        }
    }
    __syncthreads();                               // staging area now reusable

    // Wo * (1/48) -> lds[9504..10527]
    #pragma unroll
    for (int e = 0; e < 4; ++e)
        lds[9504 + e * 256 + tid] = Wo[e * 256 + tid] * (1.f / nN);

    const int ptE = tid >> 3, dqE = tid & 7, d0 = dqE * 4;
    const float4 b4 = *(const float4*)(bo + d0);
    const float vmm = vm[b * nN + m];

    for (int h = 0; h < 2; ++h) {
        if ((i3 >> 1) == h) {                      // write this half's z
            int r0 = il0 - 12 * h;                 // 0 or 6
            #pragma unroll
            for (int l = 0; l < 6; ++l)
                #pragma unroll
                for (int u = 0; u < 12; ++u)
                    lds[((r0 + l) * 24 + jl0 + u) * 33 + c] = acc[l][u];
        }
        __syncthreads();

        float oac[9][4];
        #pragma unroll
        for (int u = 0; u < 9; ++u)
            #pragma unroll
            for (int d = 0; d < 4; ++d) oac[u][d] = 0.f;
        #pragma unroll
        for (int c2 = 0; c2 < 32; ++c2) {
            float4 wo4 = *(const float4*)(lds + 9504 + c2 * 32 + d0);
            float zv[9];
            #pragma unroll
            for (int u = 0; u < 9; ++u) zv[u] = lds[(ptE * 9 + u) * 33 + c2];
            #pragma unroll
            for (int u = 0; u < 9; ++u) {
                oac[u][0] = fmaf(zv[u], wo4.x, oac[u][0]);
                oac[u][1] = fmaf(zv[u], wo4.y, oac[u][1]);
                oac[u][2] = fmaf(zv[u], wo4.z, oac[u][2]);
                oac[u][3] = fmaf(zv[u], wo4.w, oac[u][3]);
            }
        }
        #pragma unroll
        for (int u = 0; u < 9; ++u) {
            int p = ptE * 9 + u;
            int rl = p / 24, jl = p - rl * 24;
            int gi = it * 24 + 12 * h + rl, gj = jt * 24 + jl;
            float mk = vm[b * nN + gi] * vm[b * nN + gj] * vmm;
            float4 o4;
            o4.x = fmaxf(oac[u][0] + b4.x, 0.f) * mk;
            o4.y = fmaxf(oac[u][1] + b4.y, 0.f) * mk;
            o4.z = fmaxf(oac[u][2] + b4.z, 0.f) * mk;
            o4.w = fmaxf(oac[u][3] + b4.w, 0.f) * mk;
            *(float4*)(tout + posbase + (size_t)gi * SI_ + (size_t)gj * SJ_ + d0) = o4;
        }
        if (h == 0) __syncthreads();               // before half-1 overwrites z
    }
}

// ---------------------------------------------------------------------------
// Final snconv2 (C_out = 16), masked, direct to d_out.  (R1 verbatim.)
__global__ __launch_bounds__(256) void k_final(
    const float* __restrict__ t, const float* __restrict__ vm,
    const float* __restrict__ drp, const float* __restrict__ ccp, const float* __restrict__ tbp,
    const float* __restrict__ W0, const float* __restrict__ W1,
    float* __restrict__ out)
{
    __shared__ float sA[128 * 34], sB[128 * 34];
    const int tid = threadIdx.x;
    const long base = (long)blockIdx.x * 128;
    for (int rep = 0; rep < 4; ++rep) {
        int q = rep * 256 + tid; int pl = q >> 3, cq = q & 7;
        long p = base + pl;
        float4 a = *(const float4*)(t + p * nC + cq * 4);
        int o = pl * 34 + cq * 4;
        sA[o + 0] = a.x; sA[o + 1] = a.y; sA[o + 2] = a.z; sA[o + 3] = a.w;
        int b, i, j, m; decodePos((int)p, b, i, j, m);
        long pT = ((long)(b * nN + j) * nN + i) * nN + m;
        float4 t4 = *(const float4*)(t + pT * nC + cq * 4);
        sB[o + 0] = t4.x; sB[o + 1] = t4.y; sB[o + 2] = t4.z; sB[o + 3] = t4.w;
    }
    __syncthreads();
    const int pt = tid >> 3, dq = tid & 7;
    const int p0 = pt * 4, d0 = dq * 2;
    float wc[32][2], acc[4][2];
    #pragma unroll
    for (int l = 0; l < 4; ++l) { acc[l][0] = 0.f; acc[l][1] = 0.f; }

    #pragma unroll
    for (int c2 = 0; c2 < 32; ++c2) {
        float2 q2 = *(const float2*)(W0 + c2 * 16 + d0);
        wc[c2][0] = q2.x; wc[c2][1] = q2.y;
    }
    #pragma unroll
    for (int c2 = 0; c2 < 32; ++c2) {
        float t0 = sA[(p0 + 0) * 34 + c2], t1 = sA[(p0 + 1) * 34 + c2];
        float t2 = sA[(p0 + 2) * 34 + c2], t3 = sA[(p0 + 3) * 34 + c2];
        acc[0][0] = fmaf(t0, wc[c2][0], acc[0][0]); acc[0][1] = fmaf(t0, wc[c2][1], acc[0][1]);
        acc[1][0] = fmaf(t1, wc[c2][0], acc[1][0]); acc[1][1] = fmaf(t1, wc[c2][1], acc[1][1]);
        acc[2][0] = fmaf(t2, wc[c2][0], acc[2][0]); acc[2][1] = fmaf(t2, wc[c2][1], acc[2][1]);
        acc[3][0] = fmaf(t3, wc[c2][0], acc[3][0]); acc[3][1] = fmaf(t3, wc[c2][1], acc[3][1]);
    }
    #pragma unroll
    for (int c2 = 0; c2 < 32; ++c2) {
        float2 q2 = *(const float2*)(W1 + c2 * 16 + d0);
        wc[c2][0] = q2.x; wc[c2][1] = q2.y;
    }
    #pragma unroll
    for (int c2 = 0; c2 < 32; ++c2) {
        float t0 = sB[(p0 + 0) * 34 + c2], t1 = sB[(p0 + 1) * 34 + c2];
        float t2 = sB[(p0 + 2) * 34 + c2], t3 = sB[(p0 + 3) * 34 + c2];
        acc[0][0] = fmaf(t0, wc[c2][0], acc[0][0]); acc[0][1] = fmaf(t0, wc[c2][1], acc[0][1]);
        acc[1][0] = fmaf(t1, wc[c2][0], acc[1][0]); acc[1][1] = fmaf(t1, wc[c2][1], acc[1][1]);
        acc[2][0] = fmaf(t2, wc[c2][0], acc[2][0]); acc[2][1] = fmaf(t2, wc[c2][1], acc[2][1]);
        acc[3][0] = fmaf(t3, wc[c2][0], acc[3][0]); acc[3][1] = fmaf(t3, wc[c2][1], acc[3][1]);
    }
    #pragma unroll
    for (int l = 0; l < 4; ++l) {
        int p = (int)base + p0 + l;
        int b, i, j, m; decodePos(p, b, i, j, m);
        float2 d2 = *(const float2*)(drp + (size_t)((b * nN + i) * nN + m) * 16 + d0);
        float2 cc2 = *(const float2*)(ccp + (size_t)((b * nN + j) * nN + m) * 16 + d0);
        float2 tb2 = *(const float2*)(tbp + (size_t)(b * nN + m) * 16 + d0);
        float mk = vm[b * nN + i] * vm[b * nN + j] * vm[b * nN + m];
        float2 o2;
        o2.x = (acc[l][0] + d2.x + cc2.x + tb2.x) * mk;
        o2.y = (acc[l][1] + d2.y + cc2.y + tb2.y) * mk;
        *(float2*)(out + (size_t)p * 16 + d0) = o2;
    }
}

} // anonymous namespace

// ---------------------------------------------------------------------------
extern "C" void kernel_launch(void* const* d_in, const int* in_sizes, int n_in,
                              void* d_out, int out_size, void* d_ws, size_t ws_size,
                              hipStream_t stream)
{
    (void)in_sizes; (void)n_in; (void)out_size; (void)ws_size;
    const float* x    = (const float*)d_in[0];
    const void*  mask = d_in[1];
    const float* bW0  = (const float*)d_in[2];
    const float* bb0  = (const float*)d_in[3];
    const float* lvW0 = (const float*)d_in[4];
    const float* lvb0 = (const float*)d_in[5];
    const float* lwW0 = (const float*)d_in[6];
    const float* lwb0 = (const float*)d_in[7];
    const float* loW0 = (const float*)d_in[8];
    const float* lob0 = (const float*)d_in[9];
    const float* bW1  = (const float*)d_in[10];
    const float* bb1  = (const float*)d_in[11];
    const float* lvW1 = (const float*)d_in[12];
    const float* lvb1 = (const float*)d_in[13];
    const float* lwW1 = (const float*)d_in[14];
    const float* lwb1 = (const float*)d_in[15];
    const float* loW1 = (const float*)d_in[16];
    const float* lob1 = (const float*)d_in[17];
    const float* fW   = (const float*)d_in[18];
    const float* fb   = (const float*)d_in[19];

    float* ws  = (float*)d_ws;
    float* t     = ws;                         // 14155776
    float* v     = ws + 14155776L;             // 14155776
    float* w     = ws + 28311552L;             // 14155776
    float* rows  = ws + 42467328L;             // 294912
    float* cols4 = rows + 294912;              // 4 * 294912
    float* diag  = cols4 + 4 * 294912;         // 294912
    float* tot4  = diag + 294912;              // 4 * 6144
    float* dr    = tot4 + 4 * 6144;            // 294912
    float* cc    = dr + 294912;                // 294912
    float* tb    = cc + 294912;                // 6144
    float* S     = tb + 6144;                  // 128
    float* vm    = S + 128;                    // 192
    float* out   = (float*)d_out;

    k_prep<<<1, 256, 0, stream>>>(x, mask, vm, S);
    k_mix0<<<36, 256, 0, stream>>>(x, S, bW0, bb0, dr, cc, tb);
    k_vw<0><<<3456, 256, 0, stream>>>(x, vm, dr, cc, tb, bW0, bW0 + 1024,
                                      lvW0, lvb0, lwW0, lwb0, v, w);
    k_z<<<768, 256, 0, stream>>>(v, w, loW0, lob0, vm, t);
    k_red4<<<768, 256, 0, stream>>>(t, rows, cols4, diag, tot4);
    k_mix<32><<<36, 256, 0, stream>>>(diag, rows, cols4, tot4, bW1, bb1, dr, cc, tb);

    k_vw<1><<<3456, 256, 0, stream>>>(t, vm, dr, cc, tb, bW1, bW1 + 1024,
                                      lvW1, lvb1, lwW1, lwb1, v, w);
    k_z<<<768, 256, 0, stream>>>(v, w, loW1, lob1, vm, t);
    k_red4<<<768, 256, 0, stream>>>(t, rows, cols4, diag, tot4);
    k_mix<16><<<36, 256, 0, stream>>>(diag, rows, cols4, tot4, fW, fb, dr, cc, tb);
    k_final<<<3456, 256, 0, stream>>>(t, vm, dr, cc, tb, fW, fW + 512, out);
}